// Round 7
// baseline (2137.196 us; speedup 1.0000x reference)
//
#include <hip/hip_runtime.h>

// ---- static config (mirrors reference) ----
#define BB   2
#define NN   8192
#define KNN  40
#define SENT 8192
#define G0   17          // ceil coords for dl=0.06, pts in [0,1)
#define G1   9           // for dl=0.12
#define G0_3 (G0*G0*G0)  // 4913
#define G1_3 (G1*G1*G1)  // 729

// ball-query CSR grids: G = floor(1/r) so cell = 1/G >= r -> +-1 cells cover
#define GA   13          // r = 0.075  (conv0, pool0) supports = pts
#define GB   6           // r = 0.15   (up0, conv1, pool1) supports = pts1
#define GC   3           // r = 0.3    (up1, conv2) supports = pts2
#define GA_3 (GA*GA*GA)  // 2197
#define GB_3 (GB*GB*GB)  // 216
#define GC_3 (GC*GC*GC)  // 27

typedef unsigned long long ull;
typedef unsigned int       u32;
typedef unsigned short     u16;

// d2 exactly as numpy: (dx*dx + dy*dy) + dz*dz, no FMA contraction
__device__ __forceinline__ float sqdist(float qx, float qy, float qz,
                                        float sx, float sy, float sz) {
    float dx = __fsub_rn(qx, sx);
    float dy = __fsub_rn(qy, sy);
    float dz = __fsub_rn(qz, sz);
    return __fadd_rn(__fadd_rn(__fmul_rn(dx, dx), __fmul_rn(dy, dy)),
                     __fmul_rn(dz, dz));
}

// cell index, IDENTICAL function in build and query (only consistency matters)
__device__ __forceinline__ int cell1(float p, float Gf, int G) {
    int c = (int)floorf(__fmul_rn(p, Gf));
    return min(max(c, 0), G - 1);
}

// prep: copy pts -> out_points[0], fill layer-2 pool/up with SENTINEL, len[0]
__global__ void prep_kernel(const float* __restrict__ pts, float* __restrict__ dout) {
    const size_t PN = (size_t)BB * NN * 3;
    const size_t IN = (size_t)BB * NN * KNN;
    float* out_points0 = dout;
    float* out_pool2   = dout + 3 * PN + 3 * IN + 2 * IN;
    float* out_up2     = dout + 3 * PN + 6 * IN + 2 * IN;
    float* out_len     = dout + 3 * PN + 9 * IN;
    int i = blockIdx.x * 256 + threadIdx.x;
    if (i < (int)PN) out_points0[i] = pts[i];
    if (i < (int)IN) {
        out_pool2[i] = (float)SENT;
        out_up2[i]   = (float)SENT;
    }
    if (i == 0) { out_len[0] = (float)NN; out_len[1] = (float)NN; }
}

// ---- CSR build over supports: cnt -> exclusive scan -> scatter ----
// One 1024-thread block per batch.  Scatter order within a cell is
// nondeterministic (LDS atomics) — harmless: top-40 selection by full
// (d2,idx) key is a SET operation, enumeration-order independent.
__global__ __launch_bounds__(1024) void csr_build(
    const float* __restrict__ pts, const int* __restrict__ len_ptr, int len_const,
    int G, int G3, int* __restrict__ off, int* __restrict__ lst) {
    __shared__ int scnt[GA_3];   // max grid 2197 cells
    __shared__ int soff[GA_3];
    __shared__ int wsum[16];
    int b = blockIdx.x;
    int t = threadIdx.x;
    int len = len_ptr ? len_ptr[b] : len_const;
    const float* pb = pts + (size_t)b * NN * 3;
    float Gf = (float)G;
    for (int v = t; v < G3; v += 1024) scnt[v] = 0;
    __syncthreads();
    for (int i = t; i < len; i += 1024) {
        int c = (cell1(pb[i * 3], Gf, G) * G + cell1(pb[i * 3 + 1], Gf, G)) * G
                + cell1(pb[i * 3 + 2], Gf, G);
        atomicAdd(&scnt[c], 1);
    }
    __syncthreads();
    // exclusive scan of scnt -> soff (chunk-per-thread + shfl block scan)
    int per = (G3 + 1023) >> 10;
    int start = t * per, end = min(start + per, G3);
    if (start > G3) start = G3;
    int csum = 0;
    for (int v = start; v < end; ++v) csum += scnt[v];
    int lane = t & 63, wid = t >> 6;
    int inc = csum;
    for (int d = 1; d < 64; d <<= 1) {
        int u = __shfl_up(inc, d);
        if (lane >= d) inc += u;
    }
    if (lane == 63) wsum[wid] = inc;
    __syncthreads();
    if (t < 16) {
        int wv = wsum[t];
        for (int d = 1; d < 16; d <<= 1) {
            int u = __shfl_up(wv, d);
            if (t >= d) wv += u;
        }
        wsum[t] = wv;
    }
    __syncthreads();
    int excl = inc - csum + (wid ? wsum[wid - 1] : 0);
    int run = excl;
    for (int v = start; v < end; ++v) { soff[v] = run; run += scnt[v]; }
    __syncthreads();
    int* offb = off + (size_t)b * (G3 + 1);
    for (int v = t; v < G3; v += 1024) offb[v] = soff[v];
    if (t == 0) offb[G3] = len;
    __syncthreads();                       // done reading scnt as counts
    for (int v = t; v < G3; v += 1024) scnt[v] = 0;   // reuse as cursors
    __syncthreads();
    int* lstb = lst + (size_t)b * NN;
    for (int i = t; i < len; i += 1024) {
        int c = (cell1(pb[i * 3], Gf, G) * G + cell1(pb[i * 3 + 1], Gf, G)) * G
                + cell1(pb[i * 3 + 2], Gf, G);
        int pos = soff[c] + atomicAdd(&scnt[c], 1);
        lstb[pos] = i;
    }
}

// ---- 40 named register slots for the sorted top-40 key list ----
#define FORALL_K(M) \
    M(0,k00) M(1,k01) M(2,k02) M(3,k03) M(4,k04) M(5,k05) M(6,k06) M(7,k07) \
    M(8,k08) M(9,k09) M(10,k10) M(11,k11) M(12,k12) M(13,k13) M(14,k14) M(15,k15) \
    M(16,k16) M(17,k17) M(18,k18) M(19,k19) M(20,k20) M(21,k21) M(22,k22) M(23,k23) \
    M(24,k24) M(25,k25) M(26,k26) M(27,k27) M(28,k28) M(29,k29) M(30,k30) M(31,k31) \
    M(32,k32) M(33,k33) M(34,k34) M(35,k35) M(36,k36) M(37,k37) M(38,k38) M(39,k39)

#define SW1(K) { bool sw_ = ck < K; ull t_ = sw_ ? K : ck; K = sw_ ? ck : K; ck = t_; }

// ---- grid-pruned radius ball query, one THREAD per query ----
//
// Key = (f32_bits(d2) << 13) | idx (d2>=0: float bits order-monotone; idx<8192
// fits 13 bits).  u64 compare == (d2, idx) lex == reference's stable top_k
// tie-break.  Empty slot = all-ones (INITK) -> SENT on output.
//
// R7: candidate PRUNING via CSR voxel grid (cell >= r): only the 27
// neighboring cells can contain in-range supports (coverage: |dq|<=r<=cell
// -> cell coords differ by <=1; f32-rounding margin r*G<=0.975 << 1-27eps).
// Unclamped neighbor coords + skip => each support enumerated at most once
// (no duplicate keys).  Selection of the 40 smallest keys is enumeration-
// order independent => BIT-IDENTICAL to the exhaustive scan, with ~80x
// (conv0) fewer distance tests.  No LDS, no barriers, no merge.
__global__ __launch_bounds__(64, 1) void bq_grid(
    const float* __restrict__ qpts, const int* __restrict__ qlen_ptr, int qlen_const,
    const float* __restrict__ spts, const int* __restrict__ off,
    const int* __restrict__ lst, int G, int G3, float r2,
    float* __restrict__ out) {
    const ull INITK = ~0ull;
    int b = blockIdx.y;
    int qi = blockIdx.x * 64 + threadIdx.x;       // < NN by grid construction
    int qlen = qlen_ptr ? qlen_ptr[b] : qlen_const;

#define DECL_K(I,K) ull K = INITK;
    FORALL_K(DECL_K)
#undef DECL_K

    bool qvalid = qi < qlen;
    const float* qp = qpts + ((size_t)b * NN + qi) * 3;
    float qx = qp[0], qy = qp[1], qz = qp[2];     // padded rows: zeros, safe
    float Gf = (float)G;
    int cx = cell1(qx, Gf, G), cy = cell1(qy, Gf, G), cz = cell1(qz, Gf, G);
    const int* offb = off + (size_t)b * (G3 + 1);
    const int* lstb = lst + (size_t)b * NN;
    const float* sp = spts + (size_t)b * NN * 3;

#pragma unroll 1
    for (int d = 0; d < 27; ++d) {                // uniform trip count
        int dz = d % 3 - 1, dy = (d / 3) % 3 - 1, dxx = d / 9 - 1;
        int x = cx + dxx, y = cy + dy, z = cz + dz;
        bool ok = qvalid & ((unsigned)x < (unsigned)G)
                         & ((unsigned)y < (unsigned)G)
                         & ((unsigned)z < (unsigned)G);
        int c = ok ? (x * G + y) * G + z : 0;
        int s = ok ? offb[c] : 0;
        int e = ok ? offb[c + 1] : 0;
        for (; s < e; ++s) {                      // divergent, exec-masked
            int idx = lstb[s];
            float sx = sp[idx * 3], sy = sp[idx * 3 + 1], sz = sp[idx * 3 + 2];
            float d2 = sqdist(qx, qy, qz, sx, sy, sz);
            if (d2 <= r2) {                       // ref keeps d2 <= r^2
                ull ck = (((ull)__float_as_uint(d2)) << 13) | (ull)(u32)idx;
                if (ck < k39) {                   // prune: not better than 40th
                    // carry-swap insertion; __any early exits are over ACTIVE
                    // lanes (inserting INITK is a no-op, so skipping is exact)
                    SW1(k00) SW1(k01) SW1(k02) SW1(k03) SW1(k04) SW1(k05) SW1(k06) SW1(k07)
                    if (__any(ck != INITK)) {
                        SW1(k08) SW1(k09) SW1(k10) SW1(k11) SW1(k12) SW1(k13) SW1(k14) SW1(k15)
                        if (__any(ck != INITK)) {
                            SW1(k16) SW1(k17) SW1(k18) SW1(k19) SW1(k20) SW1(k21) SW1(k22) SW1(k23)
                            if (__any(ck != INITK)) {
                                SW1(k24) SW1(k25) SW1(k26) SW1(k27) SW1(k28) SW1(k29) SW1(k30) SW1(k31)
                                if (__any(ck != INITK)) {
                                    SW1(k32) SW1(k33) SW1(k34) SW1(k35) SW1(k36) SW1(k37) SW1(k38) SW1(k39)
                                }
                            }
                        }
                    }
                }
            }
        }
    }
    // write 40 indices (INITK -> SENT); real d2 bits never == 0xFFFFFFFF
    float* op = out + ((size_t)b * NN + qi) * KNN;
#define OUT_K(I,K) op[I] = ((u32)(K >> 13) == 0xFFFFFFFFu) ? (float)SENT \
                                                           : (float)(int)(K & 0x1FFFu);
    FORALL_K(OUT_K)
#undef OUT_K
}

// per-point voxel id (f32 division, f32 dl)
__global__ void vid_kernel(const float* __restrict__ pts,
                           const int* __restrict__ len_ptr, int len_const,
                           int* __restrict__ vid, float dlf, int G) {
    int b = blockIdx.y;
    int i = blockIdx.x * 256 + threadIdx.x;
    int len = len_ptr ? len_ptr[b] : len_const;
    if (i >= len) return;
    const float* p = pts + ((size_t)b * NN + i) * 3;
    int cx = (int)floorf(__fdiv_rn(p[0], dlf));
    int cy = (int)floorf(__fdiv_rn(p[1], dlf));
    int cz = (int)floorf(__fdiv_rn(p[2], dlf));
    cx = min(max(cx, 0), G - 1);
    cy = min(max(cy, 0), G - 1);
    cz = min(max(cz, 0), G - 1);
    vid[(size_t)b * NN + i] = (cx * G + cy) * G + cz;  // lexicographic == ref key order
}

// deterministic per-voxel accumulation, wave-per-voxel (bit-exact ordering)
__global__ __launch_bounds__(256) void vscan_kernel(
    const float* __restrict__ pts, const int* __restrict__ vid,
    const int* __restrict__ len_ptr, int len_const,
    float* __restrict__ vsum, int* __restrict__ vcnt, int G3) {
    int b = blockIdx.y;
    int t = threadIdx.x;
    int w = t >> 6, lane = t & 63;
    int v = blockIdx.x * 4 + w;          // one wave per voxel
    if (v >= G3) return;                 // wave-uniform, no syncthreads in kernel
    int len = len_ptr ? len_ptr[b] : len_const;
    const int* vb = vid + (size_t)b * NN;
    const float* pb = pts + (size_t)b * NN * 3;
    float sx = 0.f, sy = 0.f, sz = 0.f;
    int c = 0;
    for (int base = 0; base < len; base += 64) {
        int i = base + lane;
        int myv = (i < len) ? vb[i] : -1;
        ull m = __ballot(myv == v);
        while (m) {                       // m wave-uniform; body runs on all lanes
            int bit = __ffsll(m) - 1;
            m &= m - 1;                   // clear lowest set bit -> ascending order
            int idx = base + bit;
            sx = __fadd_rn(sx, pb[idx * 3]);
            sy = __fadd_rn(sy, pb[idx * 3 + 1]);
            sz = __fadd_rn(sz, pb[idx * 3 + 2]);
            ++c;
        }
    }
    if (lane == 0) {
        size_t o = (size_t)b * G3 + v;
        vsum[o * 3]     = sx;
        vsum[o * 3 + 1] = sy;
        vsum[o * 3 + 2] = sz;
        vcnt[o] = c;
    }
}

// compact occupied voxels in id (== key) order -> padded means + length.
// MEAN = sum * f32(1/cnt) (reciprocal-multiply — matches the np reference
// EXACTLY; verified bit-exact in R14. DO NOT change to true division.)
__global__ __launch_bounds__(1024) void compact_kernel(
    const float* __restrict__ vsum, const int* __restrict__ vcnt, int G3,
    float* __restrict__ out_pts, int* __restrict__ len_dev,
    float* __restrict__ len_out_f) {
    __shared__ int wsum[16];
    int b = blockIdx.x;
    int t = threadIdx.x;
    int per = (G3 + 1023) >> 10;
    int start = t * per;
    int end = min(start + per, G3);
    if (start > G3) start = G3;
    int c = 0;
    for (int v = start; v < end; ++v) c += (vcnt[(size_t)b * G3 + v] > 0);
    int lane = t & 63, wid = t >> 6;
    int inc = c;
    for (int d = 1; d < 64; d <<= 1) {
        int u = __shfl_up(inc, d);
        if (lane >= d) inc += u;
    }
    if (lane == 63) wsum[wid] = inc;
    __syncthreads();
    if (t < 16) {
        int wv = wsum[t];
        for (int d = 1; d < 16; d <<= 1) {
            int u = __shfl_up(wv, d);
            if (t >= d) wv += u;
        }
        wsum[t] = wv;
    }
    __syncthreads();
    int excl = inc - c + (wid ? wsum[wid - 1] : 0);
    int total = wsum[15];
    int off = excl;
    for (int v = start; v < end; ++v) {
        int cn = vcnt[(size_t)b * G3 + v];
        if (cn > 0) {
            float rinv = __frcp_rn((float)cn);
            const float* sp = vsum + ((size_t)b * G3 + v) * 3;
            float* op = out_pts + ((size_t)b * NN + off) * 3;
            op[0] = __fmul_rn(sp[0], rinv);
            op[1] = __fmul_rn(sp[1], rinv);
            op[2] = __fmul_rn(sp[2], rinv);
            ++off;
        }
    }
    for (int r = total + t; r < NN; r += 1024) {
        float* op = out_pts + ((size_t)b * NN + r) * 3;
        op[0] = 0.f; op[1] = 0.f; op[2] = 0.f;
    }
    if (t == 0) {
        len_dev[b] = total;
        len_out_f[b] = (float)total;
    }
}

extern "C" void kernel_launch(void* const* d_in, const int* in_sizes, int n_in,
                              void* d_out, int out_size, void* d_ws, size_t ws_size,
                              hipStream_t stream) {
    const float* pts = (const float*)d_in[0];
    float* dout = (float*)d_out;
    const size_t PN = (size_t)BB * NN * 3;     // 49152
    const size_t IN = (size_t)BB * NN * KNN;   // 655360
    float* out_points = dout;
    float* out_neigh  = dout + 3 * PN;
    float* out_pool   = out_neigh + 3 * IN;
    float* out_up     = out_pool + 3 * IN;
    float* out_len    = out_up + 3 * IN;
    float* pts1 = out_points + PN;       // layer-1 points live directly in d_out
    float* pts2 = out_points + 2 * PN;

    // workspace layout (everything written before read -> no memset needed)
    int*   vid0  = (int*)d_ws;                               // BB*NN
    int*   vid1  = vid0 + (size_t)BB * NN;                   // BB*NN
    float* vsum0 = (float*)(vid1 + (size_t)BB * NN);         // BB*G0_3*3
    int*   vcnt0 = (int*)(vsum0 + (size_t)BB * G0_3 * 3);    // BB*G0_3
    float* vsum1 = (float*)(vcnt0 + (size_t)BB * G0_3);      // BB*G1_3*3
    int*   vcnt1 = (int*)(vsum1 + (size_t)BB * G1_3 * 3);    // BB*G1_3
    int*   len1  = vcnt1 + (size_t)BB * G1_3;
    int*   len2  = len1 + BB;
    // ball-query CSR arrays
    int*   offA  = len2 + BB;                                // BB*(GA_3+1)
    int*   lstA  = offA + (size_t)BB * (GA_3 + 1);           // BB*NN
    int*   offB  = lstA + (size_t)BB * NN;                   // BB*(GB_3+1)
    int*   lstB  = offB + (size_t)BB * (GB_3 + 1);           // BB*NN
    int*   offC  = lstB + (size_t)BB * NN;                   // BB*(GC_3+1)
    int*   lstC  = offC + (size_t)BB * (GC_3 + 1);           // BB*NN

    // mirror Python double-precision scalar arithmetic, then narrow to f32
    double r_normal = 0.03 * 2.5;                 // 0.075
    double r0 = r_normal;
    double dl0 = 2.0 * r_normal / 2.5;            // 0.06
    float r2_0   = (float)(r0 * r0);
    float r2_up0 = (float)((2.0 * r0) * (2.0 * r0));
    float dlf0   = (float)dl0;
    r_normal *= 2.0;                              // 0.15
    double r1 = r_normal;
    double dl1 = 2.0 * r_normal / 2.5;            // 0.12
    float r2_1   = (float)(r1 * r1);
    float r2_up1 = (float)((2.0 * r1) * (2.0 * r1));
    float dlf1   = (float)dl1;
    r_normal *= 2.0;                              // 0.3
    float r2_2 = (float)(r_normal * r_normal);

    dim3 qgrid(NN / 64, BB);            // bq_grid: 1 thread per query
    dim3 vxgrid(NN / 256, BB);
    dim3 vsgrid0((G0_3 + 3) / 4, BB);   // one wave (of 4 per block) per voxel
    dim3 vsgrid1((G1_3 + 3) / 4, BB);

    prep_kernel<<<(int)((IN + 255) / 256), 256, 0, stream>>>(pts, dout);
    // layer 0  (CSR_A: supports = pts, G=13, serves r=0.075 calls)
    csr_build<<<BB, 1024, 0, stream>>>(pts, nullptr, NN, GA, GA_3, offA, lstA);
    bq_grid<<<qgrid, 64, 0, stream>>>(pts, nullptr, NN, pts, offA, lstA,
                                      GA, GA_3, r2_0, out_neigh + 0 * IN);
    vid_kernel<<<vxgrid, 256, 0, stream>>>(pts, nullptr, NN, vid0, dlf0, G0);
    vscan_kernel<<<vsgrid0, 256, 0, stream>>>(pts, vid0, nullptr, NN, vsum0, vcnt0, G0_3);
    compact_kernel<<<BB, 1024, 0, stream>>>(vsum0, vcnt0, G0_3, pts1, len1, out_len + 2);
    bq_grid<<<qgrid, 64, 0, stream>>>(pts1, len1, 0, pts, offA, lstA,
                                      GA, GA_3, r2_0, out_pool + 0 * IN);
    // CSR_B: supports = pts1, G=6, serves r=0.15 calls (up0, conv1, pool1)
    csr_build<<<BB, 1024, 0, stream>>>(pts1, len1, 0, GB, GB_3, offB, lstB);
    bq_grid<<<qgrid, 64, 0, stream>>>(pts, nullptr, NN, pts1, offB, lstB,
                                      GB, GB_3, r2_up0, out_up + 0 * IN);
    // layer 1
    vid_kernel<<<vxgrid, 256, 0, stream>>>(pts1, len1, 0, vid1, dlf1, G1);
    vscan_kernel<<<vsgrid1, 256, 0, stream>>>(pts1, vid1, len1, 0, vsum1, vcnt1, G1_3);
    compact_kernel<<<BB, 1024, 0, stream>>>(vsum1, vcnt1, G1_3, pts2, len2, out_len + 4);
    bq_grid<<<qgrid, 64, 0, stream>>>(pts1, len1, 0, pts1, offB, lstB,
                                      GB, GB_3, r2_1, out_neigh + 1 * IN);
    bq_grid<<<qgrid, 64, 0, stream>>>(pts2, len2, 0, pts1, offB, lstB,
                                      GB, GB_3, r2_1, out_pool + 1 * IN);
    // CSR_C: supports = pts2, G=3, serves r=0.3 calls (up1, conv2)
    csr_build<<<BB, 1024, 0, stream>>>(pts2, len2, 0, GC, GC_3, offC, lstC);
    bq_grid<<<qgrid, 64, 0, stream>>>(pts1, len1, 0, pts2, offC, lstC,
                                      GC, GC_3, r2_up1, out_up + 1 * IN);
    // layer 2
    bq_grid<<<qgrid, 64, 0, stream>>>(pts2, len2, 0, pts2, offC, lstC,
                                      GC, GC_3, r2_2, out_neigh + 2 * IN);
}

// Round 8
// 579.796 us; speedup vs baseline: 3.6861x; 3.6861x over previous
//
#include <hip/hip_runtime.h>

// ---- static config (mirrors reference) ----
#define BB   2
#define NN   8192
#define KNN  40
#define SENT 8192
#define G0   17          // ceil coords for dl=0.06, pts in [0,1)
#define G1   9           // for dl=0.12
#define G0_3 (G0*G0*G0)  // 4913
#define G1_3 (G1*G1*G1)  // 729

// ball-query CSR grids: G = floor(1/r) so cell = 1/G >= r -> +-1 cells cover
#define GA   13          // r = 0.075  (conv0, pool0) supports = pts
#define GB   6           // r = 0.15   (up0, conv1, pool1) supports = pts1
#define GC   3           // r = 0.3    (up1, conv2) supports = pts2
#define GA_3 (GA*GA*GA)  // 2197
#define GB_3 (GB*GB*GB)  // 216
#define GC_3 (GC*GC*GC)  // 27

typedef unsigned long long ull;
typedef unsigned int       u32;
typedef unsigned short     u16;

// d2 exactly as numpy: (dx*dx + dy*dy) + dz*dz, no FMA contraction
__device__ __forceinline__ float sqdist(float qx, float qy, float qz,
                                        float sx, float sy, float sz) {
    float dx = __fsub_rn(qx, sx);
    float dy = __fsub_rn(qy, sy);
    float dz = __fsub_rn(qz, sz);
    return __fadd_rn(__fadd_rn(__fmul_rn(dx, dx), __fmul_rn(dy, dy)),
                     __fmul_rn(dz, dz));
}

// cell index, IDENTICAL function in build and query (only consistency matters)
__device__ __forceinline__ int cell1(float p, float Gf, int G) {
    int c = (int)floorf(__fmul_rn(p, Gf));
    return min(max(c, 0), G - 1);
}

__device__ __forceinline__ ull readlane_u64(ull x, int l) {
    u32 lo = (u32)__builtin_amdgcn_readlane((int)(u32)(x & 0xFFFFFFFFu), l);
    u32 hi = (u32)__builtin_amdgcn_readlane((int)(u32)(x >> 32), l);
    return ((ull)hi << 32) | (ull)lo;
}

// prep: copy pts -> out_points[0], fill layer-2 pool/up with SENTINEL, len[0]
__global__ void prep_kernel(const float* __restrict__ pts, float* __restrict__ dout) {
    const size_t PN = (size_t)BB * NN * 3;
    const size_t IN = (size_t)BB * NN * KNN;
    float* out_points0 = dout;
    float* out_pool2   = dout + 3 * PN + 3 * IN + 2 * IN;
    float* out_up2     = dout + 3 * PN + 6 * IN + 2 * IN;
    float* out_len     = dout + 3 * PN + 9 * IN;
    int i = blockIdx.x * 256 + threadIdx.x;
    if (i < (int)PN) out_points0[i] = pts[i];
    if (i < (int)IN) {
        out_pool2[i] = (float)SENT;
        out_up2[i]   = (float)SENT;
    }
    if (i == 0) { out_len[0] = (float)NN; out_len[1] = (float)NN; }
}

// ---- CSR build over supports: cnt -> exclusive scan -> scatter ----
// One 1024-thread block per batch.  Scatter order within a cell is
// nondeterministic (LDS atomics) — harmless: top-40 selection by full
// (d2,idx) key is a SET operation, enumeration-order independent.
__global__ __launch_bounds__(1024) void csr_build(
    const float* __restrict__ pts, const int* __restrict__ len_ptr, int len_const,
    int G, int G3, int* __restrict__ off, int* __restrict__ lst) {
    __shared__ int scnt[GA_3];   // max grid 2197 cells
    __shared__ int soff[GA_3];
    __shared__ int wsum[16];
    int b = blockIdx.x;
    int t = threadIdx.x;
    int len = len_ptr ? len_ptr[b] : len_const;
    const float* pb = pts + (size_t)b * NN * 3;
    float Gf = (float)G;
    for (int v = t; v < G3; v += 1024) scnt[v] = 0;
    __syncthreads();
    for (int i = t; i < len; i += 1024) {
        int c = (cell1(pb[i * 3], Gf, G) * G + cell1(pb[i * 3 + 1], Gf, G)) * G
                + cell1(pb[i * 3 + 2], Gf, G);
        atomicAdd(&scnt[c], 1);
    }
    __syncthreads();
    // exclusive scan of scnt -> soff (chunk-per-thread + shfl block scan)
    int per = (G3 + 1023) >> 10;
    int start = t * per, end = min(start + per, G3);
    if (start > G3) start = G3;
    int csum = 0;
    for (int v = start; v < end; ++v) csum += scnt[v];
    int lane = t & 63, wid = t >> 6;
    int inc = csum;
    for (int d = 1; d < 64; d <<= 1) {
        int u = __shfl_up(inc, d);
        if (lane >= d) inc += u;
    }
    if (lane == 63) wsum[wid] = inc;
    __syncthreads();
    if (t < 16) {
        int wv = wsum[t];
        for (int d = 1; d < 16; d <<= 1) {
            int u = __shfl_up(wv, d);
            if (t >= d) wv += u;
        }
        wsum[t] = wv;
    }
    __syncthreads();
    int excl = inc - csum + (wid ? wsum[wid - 1] : 0);
    int run = excl;
    for (int v = start; v < end; ++v) { soff[v] = run; run += scnt[v]; }
    __syncthreads();
    int* offb = off + (size_t)b * (G3 + 1);
    for (int v = t; v < G3; v += 1024) offb[v] = soff[v];
    if (t == 0) offb[G3] = len;
    __syncthreads();                       // done reading scnt as counts
    for (int v = t; v < G3; v += 1024) scnt[v] = 0;   // reuse as cursors
    __syncthreads();
    int* lstb = lst + (size_t)b * NN;
    for (int i = t; i < len; i += 1024) {
        int c = (cell1(pb[i * 3], Gf, G) * G + cell1(pb[i * 3 + 1], Gf, G)) * G
                + cell1(pb[i * 3 + 2], Gf, G);
        int pos = soff[c] + atomicAdd(&scnt[c], 1);
        lstb[pos] = i;
    }
}

// ---- grid-pruned radius ball query, one WAVE per query ----
//
// Key = (f32_bits(d2) << 13) | idx (d2>=0: float bits order-monotone; idx<8192
// fits 13 bits).  u64 compare == (d2, idx) lex == reference's stable top_k
// tie-break.  All keys are UNIQUE (idx distinct; each support enumerated at
// most once).  Empty slot = all-ones (INITK) -> SENT on output.
//
// R8: R7 proved CSR pruning bit-exact (absmax 0.0) but ran it at 1 wave/CU
// (one THREAD per query, 64-thread blocks) -> pure exposed latency.  Now one
// WAVE per query (16384 waves ~ 16/CU):
//   - lane d<27 loads its neighbor cell's CSR range in parallel
//   - wave exclusive-scan ranks all T candidates; lane takes ranks lane+64s,
//     s<8 (512/round; multiple rounds exact via old-result merge)
//   - rank -> cell by 5-step shuffle binary search (monotone excl array)
//   - r2-filter -> per-lane Batcher sort-8 of keys
//   - exact top-40: 40x wave-min extraction (u64 shfl_xor butterfly over lane
//     heads + shift-down in the unique winner lane), merged against previous
//     round's result by pointer; wave-uniform early break when all empty.
// Set semantics identical to the exhaustive scan -> bit-identical output.
__global__ __launch_bounds__(256) void bq_wave(
    const float* __restrict__ qpts, const int* __restrict__ qlen_ptr, int qlen_const,
    const float* __restrict__ spts, const int* __restrict__ off,
    const int* __restrict__ lst, int G, int G3, float r2,
    float* __restrict__ out) {
    const ull INITK = ~0ull;
    int t = threadIdx.x;
    int lane = t & 63;
    int b = blockIdx.y;
    int qi = blockIdx.x * 4 + (t >> 6);           // one wave per query
    int qlen = qlen_ptr ? qlen_ptr[b] : qlen_const;
    float* op = out + ((size_t)b * NN + qi) * KNN;
    if (qi >= qlen) {                             // wave-uniform
        if (lane < KNN) op[lane] = (float)SENT;
        return;
    }
    const float* qp = qpts + ((size_t)b * NN + qi) * 3;
    float qx = qp[0], qy = qp[1], qz = qp[2];
    float Gf = (float)G;
    int cx = cell1(qx, Gf, G), cy = cell1(qy, Gf, G), cz = cell1(qz, Gf, G);
    const int* offb = off + (size_t)b * (G3 + 1);
    const int* lstb = lst + (size_t)b * NN;
    const float* sp = spts + (size_t)b * NN * 3;

    // lane d<27: neighbor cell (z fastest -> offb reads mostly contiguous)
    int cnt = 0, cst = 0;
    if (lane < 27) {
        int dz = lane % 3 - 1, dy = (lane / 3) % 3 - 1, dxx = lane / 9 - 1;
        int x = cx + dxx, y = cy + dy, z = cz + dz;
        bool ok = ((unsigned)x < (unsigned)G) & ((unsigned)y < (unsigned)G)
                                              & ((unsigned)z < (unsigned)G);
        int c = ok ? (x * G + y) * G + z : 0;
        int s = ok ? offb[c] : 0;
        int e = ok ? offb[c + 1] : 0;
        cnt = e - s;
        cst = s;
    }
    // wave exclusive scan of cnt; excl[27..63] == T (cnt==0 there)
    int incl = cnt;
#pragma unroll
    for (int d_ = 1; d_ < 64; d_ <<= 1) {
        int u = __shfl_up(incl, d_);
        if (lane >= d_) incl += u;
    }
    int excl = incl - cnt;
    int T = __shfl(incl, 63);

    ull res = INITK;                              // lane k<40 holds k-th best
    for (int r0 = 0; r0 < T; r0 += 512) {
        ull c0 = INITK, c1 = INITK, c2 = INITK, c3 = INITK,
            c4 = INITK, c5 = INITK, c6 = INITK, c7 = INITK;
        // fill slots: global rank g = r0 + s*64 + lane (all lanes active;
        // out-of-range ranks clamped for the search, predicated at accept)
#define FILL(S, CS) {                                                          \
            int g = r0 + (S) * 64 + lane;                                      \
            bool gok = g < T;                                                  \
            int gc = gok ? g : (T - 1);                                        \
            int d = 0;                                                         \
            if (__shfl(excl, d | 16) <= gc) d |= 16;                           \
            if (__shfl(excl, d | 8)  <= gc) d |= 8;                            \
            if (__shfl(excl, d | 4)  <= gc) d |= 4;                            \
            if (__shfl(excl, d | 2)  <= gc) d |= 2;                            \
            if (__shfl(excl, d | 1)  <= gc) d |= 1;                            \
            int st = __shfl(cst, d), eg = __shfl(excl, d);                     \
            int idx = lstb[st + (gc - eg)];                                    \
            float sx = sp[idx * 3], sy = sp[idx * 3 + 1], sz = sp[idx * 3 + 2];\
            float d2 = sqdist(qx, qy, qz, sx, sy, sz);                         \
            if (gok && d2 <= r2)                                               \
                CS = (((ull)__float_as_uint(d2)) << 13) | (ull)(u32)idx;       \
        }
        FILL(0, c0) FILL(1, c1) FILL(2, c2) FILL(3, c3)
        FILL(4, c4) FILL(5, c5) FILL(6, c6) FILL(7, c7)
#undef FILL
        // per-lane Batcher sort-8 ascending (INITK sinks to the back)
#define CE(A, B) { ull lo_ = (A < B) ? A : B; ull hi_ = (A < B) ? B : A; A = lo_; B = hi_; }
        CE(c0,c1) CE(c2,c3) CE(c4,c5) CE(c6,c7)
        CE(c0,c2) CE(c1,c3) CE(c4,c6) CE(c5,c7)
        CE(c1,c2) CE(c5,c6)
        CE(c0,c4) CE(c1,c5) CE(c2,c6) CE(c3,c7)
        CE(c2,c4) CE(c3,c5)
        CE(c1,c2) CE(c3,c4) CE(c5,c6)
#undef CE
        // exact merge-extraction: wave-min over lane heads vs old result
        ull res_old = res;
        res = INITK;
        int p = 0;                                // pointer into res_old lanes
        for (int k = 0; k < KNN; ++k) {
            ull m = c0;
#pragma unroll
            for (int x_ = 1; x_ < 64; x_ <<= 1) {
                ull o_ = __shfl_xor(m, x_);
                m = (o_ < m) ? o_ : m;
            }
            ull ok_ = readlane_u64(res_old, p);   // p <= 40 < 64; lanes>=40 INITK
            ull best = (m < ok_) ? m : ok_;
            if (best == INITK) break;             // wave-uniform
            if (best == ok_) {
                ++p;
            } else if (c0 == best) {              // unique winner lane
                c0 = c1; c1 = c2; c2 = c3; c3 = c4;
                c4 = c5; c5 = c6; c6 = c7; c7 = INITK;
            }
            if (lane == k) res = best;
        }
    }
    // coalesced output: lane k writes slot k
    if (lane < KNN)
        op[lane] = (res == INITK) ? (float)SENT : (float)(int)(res & 0x1FFFu);
}

// per-point voxel id (f32 division, f32 dl)
__global__ void vid_kernel(const float* __restrict__ pts,
                           const int* __restrict__ len_ptr, int len_const,
                           int* __restrict__ vid, float dlf, int G) {
    int b = blockIdx.y;
    int i = blockIdx.x * 256 + threadIdx.x;
    int len = len_ptr ? len_ptr[b] : len_const;
    if (i >= len) return;
    const float* p = pts + ((size_t)b * NN + i) * 3;
    int cx = (int)floorf(__fdiv_rn(p[0], dlf));
    int cy = (int)floorf(__fdiv_rn(p[1], dlf));
    int cz = (int)floorf(__fdiv_rn(p[2], dlf));
    cx = min(max(cx, 0), G - 1);
    cy = min(max(cy, 0), G - 1);
    cz = min(max(cz, 0), G - 1);
    vid[(size_t)b * NN + i] = (cx * G + cy) * G + cz;  // lexicographic == ref key order
}

// deterministic per-voxel accumulation, wave-per-voxel (bit-exact ordering)
__global__ __launch_bounds__(256) void vscan_kernel(
    const float* __restrict__ pts, const int* __restrict__ vid,
    const int* __restrict__ len_ptr, int len_const,
    float* __restrict__ vsum, int* __restrict__ vcnt, int G3) {
    int b = blockIdx.y;
    int t = threadIdx.x;
    int w = t >> 6, lane = t & 63;
    int v = blockIdx.x * 4 + w;          // one wave per voxel
    if (v >= G3) return;                 // wave-uniform, no syncthreads in kernel
    int len = len_ptr ? len_ptr[b] : len_const;
    const int* vb = vid + (size_t)b * NN;
    const float* pb = pts + (size_t)b * NN * 3;
    float sx = 0.f, sy = 0.f, sz = 0.f;
    int c = 0;
    for (int base = 0; base < len; base += 64) {
        int i = base + lane;
        int myv = (i < len) ? vb[i] : -1;
        ull m = __ballot(myv == v);
        while (m) {                       // m wave-uniform; body runs on all lanes
            int bit = __ffsll(m) - 1;
            m &= m - 1;                   // clear lowest set bit -> ascending order
            int idx = base + bit;
            sx = __fadd_rn(sx, pb[idx * 3]);
            sy = __fadd_rn(sy, pb[idx * 3 + 1]);
            sz = __fadd_rn(sz, pb[idx * 3 + 2]);
            ++c;
        }
    }
    if (lane == 0) {
        size_t o = (size_t)b * G3 + v;
        vsum[o * 3]     = sx;
        vsum[o * 3 + 1] = sy;
        vsum[o * 3 + 2] = sz;
        vcnt[o] = c;
    }
}

// compact occupied voxels in id (== key) order -> padded means + length.
// MEAN = sum * f32(1/cnt) (reciprocal-multiply — matches the np reference
// EXACTLY; verified bit-exact in R14. DO NOT change to true division.)
__global__ __launch_bounds__(1024) void compact_kernel(
    const float* __restrict__ vsum, const int* __restrict__ vcnt, int G3,
    float* __restrict__ out_pts, int* __restrict__ len_dev,
    float* __restrict__ len_out_f) {
    __shared__ int wsum[16];
    int b = blockIdx.x;
    int t = threadIdx.x;
    int per = (G3 + 1023) >> 10;
    int start = t * per;
    int end = min(start + per, G3);
    if (start > G3) start = G3;
    int c = 0;
    for (int v = start; v < end; ++v) c += (vcnt[(size_t)b * G3 + v] > 0);
    int lane = t & 63, wid = t >> 6;
    int inc = c;
    for (int d = 1; d < 64; d <<= 1) {
        int u = __shfl_up(inc, d);
        if (lane >= d) inc += u;
    }
    if (lane == 63) wsum[wid] = inc;
    __syncthreads();
    if (t < 16) {
        int wv = wsum[t];
        for (int d = 1; d < 16; d <<= 1) {
            int u = __shfl_up(wv, d);
            if (t >= d) wv += u;
        }
        wsum[t] = wv;
    }
    __syncthreads();
    int excl = inc - c + (wid ? wsum[wid - 1] : 0);
    int total = wsum[15];
    int off = excl;
    for (int v = start; v < end; ++v) {
        int cn = vcnt[(size_t)b * G3 + v];
        if (cn > 0) {
            float rinv = __frcp_rn((float)cn);
            const float* sp = vsum + ((size_t)b * G3 + v) * 3;
            float* op = out_pts + ((size_t)b * NN + off) * 3;
            op[0] = __fmul_rn(sp[0], rinv);
            op[1] = __fmul_rn(sp[1], rinv);
            op[2] = __fmul_rn(sp[2], rinv);
            ++off;
        }
    }
    for (int r = total + t; r < NN; r += 1024) {
        float* op = out_pts + ((size_t)b * NN + r) * 3;
        op[0] = 0.f; op[1] = 0.f; op[2] = 0.f;
    }
    if (t == 0) {
        len_dev[b] = total;
        len_out_f[b] = (float)total;
    }
}

extern "C" void kernel_launch(void* const* d_in, const int* in_sizes, int n_in,
                              void* d_out, int out_size, void* d_ws, size_t ws_size,
                              hipStream_t stream) {
    const float* pts = (const float*)d_in[0];
    float* dout = (float*)d_out;
    const size_t PN = (size_t)BB * NN * 3;     // 49152
    const size_t IN = (size_t)BB * NN * KNN;   // 655360
    float* out_points = dout;
    float* out_neigh  = dout + 3 * PN;
    float* out_pool   = out_neigh + 3 * IN;
    float* out_up     = out_pool + 3 * IN;
    float* out_len    = out_up + 3 * IN;
    float* pts1 = out_points + PN;       // layer-1 points live directly in d_out
    float* pts2 = out_points + 2 * PN;

    // workspace layout (everything written before read -> no memset needed)
    int*   vid0  = (int*)d_ws;                               // BB*NN
    int*   vid1  = vid0 + (size_t)BB * NN;                   // BB*NN
    float* vsum0 = (float*)(vid1 + (size_t)BB * NN);         // BB*G0_3*3
    int*   vcnt0 = (int*)(vsum0 + (size_t)BB * G0_3 * 3);    // BB*G0_3
    float* vsum1 = (float*)(vcnt0 + (size_t)BB * G0_3);      // BB*G1_3*3
    int*   vcnt1 = (int*)(vsum1 + (size_t)BB * G1_3 * 3);    // BB*G1_3
    int*   len1  = vcnt1 + (size_t)BB * G1_3;
    int*   len2  = len1 + BB;
    // ball-query CSR arrays
    int*   offA  = len2 + BB;                                // BB*(GA_3+1)
    int*   lstA  = offA + (size_t)BB * (GA_3 + 1);           // BB*NN
    int*   offB  = lstA + (size_t)BB * NN;                   // BB*(GB_3+1)
    int*   lstB  = offB + (size_t)BB * (GB_3 + 1);           // BB*NN
    int*   offC  = lstB + (size_t)BB * NN;                   // BB*(GC_3+1)
    int*   lstC  = offC + (size_t)BB * (GC_3 + 1);           // BB*NN

    // mirror Python double-precision scalar arithmetic, then narrow to f32
    double r_normal = 0.03 * 2.5;                 // 0.075
    double r0 = r_normal;
    double dl0 = 2.0 * r_normal / 2.5;            // 0.06
    float r2_0   = (float)(r0 * r0);
    float r2_up0 = (float)((2.0 * r0) * (2.0 * r0));
    float dlf0   = (float)dl0;
    r_normal *= 2.0;                              // 0.15
    double r1 = r_normal;
    double dl1 = 2.0 * r_normal / 2.5;            // 0.12
    float r2_1   = (float)(r1 * r1);
    float r2_up1 = (float)((2.0 * r1) * (2.0 * r1));
    float dlf1   = (float)dl1;
    r_normal *= 2.0;                              // 0.3
    float r2_2 = (float)(r_normal * r_normal);

    dim3 qgrid(NN / 4, BB);             // bq_wave: one wave per query, 4 waves/block
    dim3 vxgrid(NN / 256, BB);
    dim3 vsgrid0((G0_3 + 3) / 4, BB);   // one wave (of 4 per block) per voxel
    dim3 vsgrid1((G1_3 + 3) / 4, BB);

    prep_kernel<<<(int)((IN + 255) / 256), 256, 0, stream>>>(pts, dout);
    // layer 0  (CSR_A: supports = pts, G=13, serves r=0.075 calls)
    csr_build<<<BB, 1024, 0, stream>>>(pts, nullptr, NN, GA, GA_3, offA, lstA);
    bq_wave<<<qgrid, 256, 0, stream>>>(pts, nullptr, NN, pts, offA, lstA,
                                       GA, GA_3, r2_0, out_neigh + 0 * IN);
    vid_kernel<<<vxgrid, 256, 0, stream>>>(pts, nullptr, NN, vid0, dlf0, G0);
    vscan_kernel<<<vsgrid0, 256, 0, stream>>>(pts, vid0, nullptr, NN, vsum0, vcnt0, G0_3);
    compact_kernel<<<BB, 1024, 0, stream>>>(vsum0, vcnt0, G0_3, pts1, len1, out_len + 2);
    bq_wave<<<qgrid, 256, 0, stream>>>(pts1, len1, 0, pts, offA, lstA,
                                       GA, GA_3, r2_0, out_pool + 0 * IN);
    // CSR_B: supports = pts1, G=6, serves r=0.15 calls (up0, conv1, pool1)
    csr_build<<<BB, 1024, 0, stream>>>(pts1, len1, 0, GB, GB_3, offB, lstB);
    bq_wave<<<qgrid, 256, 0, stream>>>(pts, nullptr, NN, pts1, offB, lstB,
                                       GB, GB_3, r2_up0, out_up + 0 * IN);
    // layer 1
    vid_kernel<<<vxgrid, 256, 0, stream>>>(pts1, len1, 0, vid1, dlf1, G1);
    vscan_kernel<<<vsgrid1, 256, 0, stream>>>(pts1, vid1, len1, 0, vsum1, vcnt1, G1_3);
    compact_kernel<<<BB, 1024, 0, stream>>>(vsum1, vcnt1, G1_3, pts2, len2, out_len + 4);
    bq_wave<<<qgrid, 256, 0, stream>>>(pts1, len1, 0, pts1, offB, lstB,
                                       GB, GB_3, r2_1, out_neigh + 1 * IN);
    bq_wave<<<qgrid, 256, 0, stream>>>(pts2, len2, 0, pts1, offB, lstB,
                                       GB, GB_3, r2_1, out_pool + 1 * IN);
    // CSR_C: supports = pts2, G=3, serves r=0.3 calls (up1, conv2)
    csr_build<<<BB, 1024, 0, stream>>>(pts2, len2, 0, GC, GC_3, offC, lstC);
    bq_wave<<<qgrid, 256, 0, stream>>>(pts1, len1, 0, pts2, offC, lstC,
                                       GC, GC_3, r2_up1, out_up + 1 * IN);
    // layer 2
    bq_wave<<<qgrid, 256, 0, stream>>>(pts2, len2, 0, pts2, offC, lstC,
                                       GC, GC_3, r2_2, out_neigh + 2 * IN);
}

// Round 9
// 301.210 us; speedup vs baseline: 7.0954x; 1.9249x over previous
//
#include <hip/hip_runtime.h>

// ---- static config (mirrors reference) ----
#define BB   2
#define NN   8192
#define KNN  40
#define SENT 8192
#define G0   17          // ceil coords for dl=0.06, pts in [0,1)
#define G1   9           // for dl=0.12
#define G0_3 (G0*G0*G0)  // 4913
#define G1_3 (G1*G1*G1)  // 729

// ball-query CSR grids: G = floor(1/r) so cell = 1/G >= r -> +-1 cells cover
#define GA   13          // r = 0.075  (conv0, pool0) supports = pts
#define GB   6           // r = 0.15   (up0, conv1, pool1) supports = pts1
#define GC   3           // r = 0.3    (up1, conv2) supports = pts2
#define GA_3 (GA*GA*GA)  // 2197
#define GB_3 (GB*GB*GB)  // 216
#define GC_3 (GC*GC*GC)  // 27

typedef unsigned long long ull;
typedef unsigned int       u32;
typedef unsigned short     u16;

// d2 exactly as numpy: (dx*dx + dy*dy) + dz*dz, no FMA contraction
__device__ __forceinline__ float sqdist(float qx, float qy, float qz,
                                        float sx, float sy, float sz) {
    float dx = __fsub_rn(qx, sx);
    float dy = __fsub_rn(qy, sy);
    float dz = __fsub_rn(qz, sz);
    return __fadd_rn(__fadd_rn(__fmul_rn(dx, dx), __fmul_rn(dy, dy)),
                     __fmul_rn(dz, dz));
}

// cell index, IDENTICAL function in build and query (only consistency matters)
__device__ __forceinline__ int cell1(float p, float Gf, int G) {
    int c = (int)floorf(__fmul_rn(p, Gf));
    return min(max(c, 0), G - 1);
}

// u64 cross-lane helpers (2x 32-bit shfl)
__device__ __forceinline__ ull shfl_u64(ull x, int src) {
    int lo = __shfl((int)(u32)x, src);
    int hi = __shfl((int)(u32)(x >> 32), src);
    return ((ull)(u32)hi << 32) | (ull)(u32)lo;
}
__device__ __forceinline__ ull shflxor_u64(ull x, int m) {
    int lo = __shfl_xor((int)(u32)x, m);
    int hi = __shfl_xor((int)(u32)(x >> 32), m);
    return ((ull)(u32)hi << 32) | (ull)(u32)lo;
}

// prep: copy pts -> out_points[0], fill layer-2 pool/up with SENTINEL, len[0]
__global__ void prep_kernel(const float* __restrict__ pts, float* __restrict__ dout) {
    const size_t PN = (size_t)BB * NN * 3;
    const size_t IN = (size_t)BB * NN * KNN;
    float* out_points0 = dout;
    float* out_pool2   = dout + 3 * PN + 3 * IN + 2 * IN;
    float* out_up2     = dout + 3 * PN + 6 * IN + 2 * IN;
    float* out_len     = dout + 3 * PN + 9 * IN;
    int i = blockIdx.x * 256 + threadIdx.x;
    if (i < (int)PN) out_points0[i] = pts[i];
    if (i < (int)IN) {
        out_pool2[i] = (float)SENT;
        out_up2[i]   = (float)SENT;
    }
    if (i == 0) { out_len[0] = (float)NN; out_len[1] = (float)NN; }
}

// ---- CSR build over supports: cnt -> exclusive scan -> scatter ----
// One 1024-thread block per batch.  Scatter order within a cell is
// nondeterministic (LDS atomics) — harmless: top-40 selection by full
// (d2,idx) key is a SET operation, enumeration-order independent.
__global__ __launch_bounds__(1024) void csr_build(
    const float* __restrict__ pts, const int* __restrict__ len_ptr, int len_const,
    int G, int G3, int* __restrict__ off, int* __restrict__ lst) {
    __shared__ int scnt[GA_3];   // max grid 2197 cells
    __shared__ int soff[GA_3];
    __shared__ int wsum[16];
    int b = blockIdx.x;
    int t = threadIdx.x;
    int len = len_ptr ? len_ptr[b] : len_const;
    const float* pb = pts + (size_t)b * NN * 3;
    float Gf = (float)G;
    for (int v = t; v < G3; v += 1024) scnt[v] = 0;
    __syncthreads();
    for (int i = t; i < len; i += 1024) {
        int c = (cell1(pb[i * 3], Gf, G) * G + cell1(pb[i * 3 + 1], Gf, G)) * G
                + cell1(pb[i * 3 + 2], Gf, G);
        atomicAdd(&scnt[c], 1);
    }
    __syncthreads();
    // exclusive scan of scnt -> soff (chunk-per-thread + shfl block scan)
    int per = (G3 + 1023) >> 10;
    int start = t * per, end = min(start + per, G3);
    if (start > G3) start = G3;
    int csum = 0;
    for (int v = start; v < end; ++v) csum += scnt[v];
    int lane = t & 63, wid = t >> 6;
    int inc = csum;
    for (int d = 1; d < 64; d <<= 1) {
        int u = __shfl_up(inc, d);
        if (lane >= d) inc += u;
    }
    if (lane == 63) wsum[wid] = inc;
    __syncthreads();
    if (t < 16) {
        int wv = wsum[t];
        for (int d = 1; d < 16; d <<= 1) {
            int u = __shfl_up(wv, d);
            if (t >= d) wv += u;
        }
        wsum[t] = wv;
    }
    __syncthreads();
    int excl = inc - csum + (wid ? wsum[wid - 1] : 0);
    int run = excl;
    for (int v = start; v < end; ++v) { soff[v] = run; run += scnt[v]; }
    __syncthreads();
    int* offb = off + (size_t)b * (G3 + 1);
    for (int v = t; v < G3; v += 1024) offb[v] = soff[v];
    if (t == 0) offb[G3] = len;
    __syncthreads();                       // done reading scnt as counts
    for (int v = t; v < G3; v += 1024) scnt[v] = 0;   // reuse as cursors
    __syncthreads();
    int* lstb = lst + (size_t)b * NN;
    for (int i = t; i < len; i += 1024) {
        int c = (cell1(pb[i * 3], Gf, G) * G + cell1(pb[i * 3 + 1], Gf, G)) * G
                + cell1(pb[i * 3 + 2], Gf, G);
        int pos = soff[c] + atomicAdd(&scnt[c], 1);
        lstb[pos] = i;
    }
}

// ---- grid-pruned radius ball query, one WAVE per query ----
//
// Key = (f32_bits(d2) << 13) | idx (d2>=0: float bits order-monotone; idx<8192
// fits 13 bits).  u64 compare == (d2, idx) lex == reference's stable top_k
// tie-break.  Keys UNIQUE (distinct idx) -> any exact sort/selection gives
// the same result.  Empty = all-ones (INITK) -> SENT on output.
//
// R9: R8's selection was a 40-iteration serial min-extraction: per iteration
// a 6-step dependent u64 shfl_xor butterfly (~480 dependent DS ops/query,
// ~8400cy chain) — the measured 48%-VALUBusy ceiling.  Replaced by parallel
// sort/merge selection, still EXACT:
//   per 512-candidate round: FILL (proven) -> per-lane sort-8 (valid keys
//   compact at slots 0..m-1) -> wave scan of m -> for each 64-key chunk:
//     - dest lane D pulls its key: binary-search owner lane over base
//       (largest-with-<=, proven pattern), bpermute 8 slots, static mux by j
//     - bitonic sort-64 (21 parallel CE steps, one key/lane)
//     - bitonic merge with running res: rb=key[63-lane]; lower=min(res,rb)
//       is the lower-64 of the union (bitonic); 6-step cleanup -> sorted res.
//       top-40(union) is contained in lower-64 => exact.
// Dependent-chain ~8x shorter; heavy calls (M~15..42) do ONE sort+merge.
__global__ __launch_bounds__(256) void bq_wave(
    const float* __restrict__ qpts, const int* __restrict__ qlen_ptr, int qlen_const,
    const float* __restrict__ spts, const int* __restrict__ off,
    const int* __restrict__ lst, int G, int G3, float r2,
    float* __restrict__ out) {
    const ull INITK = ~0ull;
    int t = threadIdx.x;
    int lane = t & 63;
    int b = blockIdx.y;
    int qi = blockIdx.x * 4 + (t >> 6);           // one wave per query
    int qlen = qlen_ptr ? qlen_ptr[b] : qlen_const;
    float* op = out + ((size_t)b * NN + qi) * KNN;
    if (qi >= qlen) {                             // wave-uniform
        if (lane < KNN) op[lane] = (float)SENT;
        return;
    }
    const float* qp = qpts + ((size_t)b * NN + qi) * 3;
    float qx = qp[0], qy = qp[1], qz = qp[2];
    float Gf = (float)G;
    int cx = cell1(qx, Gf, G), cy = cell1(qy, Gf, G), cz = cell1(qz, Gf, G);
    const int* offb = off + (size_t)b * (G3 + 1);
    const int* lstb = lst + (size_t)b * NN;
    const float* sp = spts + (size_t)b * NN * 3;

    // lane d<27: neighbor cell (z fastest -> offb reads mostly contiguous)
    int cnt = 0, cst = 0;
    if (lane < 27) {
        int dz = lane % 3 - 1, dy = (lane / 3) % 3 - 1, dxx = lane / 9 - 1;
        int x = cx + dxx, y = cy + dy, z = cz + dz;
        bool ok = ((unsigned)x < (unsigned)G) & ((unsigned)y < (unsigned)G)
                                              & ((unsigned)z < (unsigned)G);
        int c = ok ? (x * G + y) * G + z : 0;
        int s = ok ? offb[c] : 0;
        int e = ok ? offb[c + 1] : 0;
        cnt = e - s;
        cst = s;
    }
    // wave exclusive scan of cnt; excl[27..63] == T (cnt==0 there)
    int incl = cnt;
#pragma unroll
    for (int d_ = 1; d_ < 64; d_ <<= 1) {
        int u = __shfl_up(incl, d_);
        if (lane >= d_) incl += u;
    }
    int excl = incl - cnt;
    int T = __shfl(incl, 63);

    ull res = INITK;                              // lane k<40 holds k-th best
    bool have_res = false;
    for (int r0 = 0; r0 < T; r0 += 512) {
        ull c0 = INITK, c1 = INITK, c2 = INITK, c3 = INITK,
            c4 = INITK, c5 = INITK, c6 = INITK, c7 = INITK;
        // fill slots: global rank g = r0 + s*64 + lane (all lanes active;
        // out-of-range ranks clamped for the search, predicated at accept)
#define FILL(S, CS) {                                                          \
            int g = r0 + (S) * 64 + lane;                                      \
            bool gok = g < T;                                                  \
            int gc = gok ? g : (T - 1);                                        \
            int d = 0;                                                         \
            if (__shfl(excl, d | 16) <= gc) d |= 16;                           \
            if (__shfl(excl, d | 8)  <= gc) d |= 8;                            \
            if (__shfl(excl, d | 4)  <= gc) d |= 4;                            \
            if (__shfl(excl, d | 2)  <= gc) d |= 2;                            \
            if (__shfl(excl, d | 1)  <= gc) d |= 1;                            \
            int st = __shfl(cst, d), eg = __shfl(excl, d);                     \
            int idx = lstb[st + (gc - eg)];                                    \
            float sx = sp[idx * 3], sy = sp[idx * 3 + 1], sz = sp[idx * 3 + 2];\
            float d2 = sqdist(qx, qy, qz, sx, sy, sz);                         \
            if (gok && d2 <= r2)                                               \
                CS = (((ull)__float_as_uint(d2)) << 13) | (ull)(u32)idx;       \
        }
        FILL(0, c0) FILL(1, c1) FILL(2, c2) FILL(3, c3)
        FILL(4, c4) FILL(5, c5) FILL(6, c6) FILL(7, c7)
#undef FILL
        // per-lane Batcher sort-8 ascending (INITK sinks to back ->
        // valid keys compact at slots 0..m-1, j-th valid == slot j)
#define CE(A, B) { ull lo_ = (A < B) ? A : B; ull hi_ = (A < B) ? B : A; A = lo_; B = hi_; }
        CE(c0,c1) CE(c2,c3) CE(c4,c5) CE(c6,c7)
        CE(c0,c2) CE(c1,c3) CE(c4,c6) CE(c5,c7)
        CE(c1,c2) CE(c5,c6)
        CE(c0,c4) CE(c1,c5) CE(c2,c6) CE(c3,c7)
        CE(c2,c4) CE(c3,c5)
        CE(c1,c2) CE(c3,c4) CE(c5,c6)
#undef CE
        // per-lane valid count + wave exclusive scan -> base, M
        int m = (c0 != INITK) + (c1 != INITK) + (c2 != INITK) + (c3 != INITK)
              + (c4 != INITK) + (c5 != INITK) + (c6 != INITK) + (c7 != INITK);
        int incm = m;
#pragma unroll
        for (int d_ = 1; d_ < 64; d_ <<= 1) {
            int u = __shfl_up(incm, d_);
            if (lane >= d_) incm += u;
        }
        int base = incm - m;
        int M = __shfl(incm, 63);
        int npass = (M + 63) >> 6;                // wave-uniform
        for (int p = 0; p < npass; ++p) {
            int D = p * 64 + lane;
            bool dok = D < M;
            int Dc = dok ? D : (M - 1);           // M >= 1 here
            // owner lane = largest l with base_l <= Dc (base non-decreasing;
            // owner property: Dc < base_l + m_l -- same proven pattern as FILL)
            int l = 0;
            if (__shfl(base, l | 32) <= Dc) l |= 32;
            if (__shfl(base, l | 16) <= Dc) l |= 16;
            if (__shfl(base, l | 8)  <= Dc) l |= 8;
            if (__shfl(base, l | 4)  <= Dc) l |= 4;
            if (__shfl(base, l | 2)  <= Dc) l |= 2;
            if (__shfl(base, l | 1)  <= Dc) l |= 1;
            int j = Dc - __shfl(base, l);         // slot within owner, 0..7
            // pull all 8 slots from owner, static 3-level mux by j (rule #20)
            ull p0 = shfl_u64(c0, l), p1 = shfl_u64(c1, l);
            ull p2 = shfl_u64(c2, l), p3 = shfl_u64(c3, l);
            ull p4 = shfl_u64(c4, l), p5 = shfl_u64(c5, l);
            ull p6 = shfl_u64(c6, l), p7 = shfl_u64(c7, l);
            ull a0 = (j & 1) ? p1 : p0;
            ull a1 = (j & 1) ? p3 : p2;
            ull a2 = (j & 1) ? p5 : p4;
            ull a3 = (j & 1) ? p7 : p6;
            ull b0 = (j & 2) ? a1 : a0;
            ull b1 = (j & 2) ? a3 : a2;
            ull key = (j & 4) ? b1 : b0;
            if (!dok) key = INITK;
            // bitonic sort-64, one key per lane, ascending
#pragma unroll
            for (int k = 2; k <= 64; k <<= 1) {
#pragma unroll
                for (int jj = k >> 1; jj > 0; jj >>= 1) {
                    ull other = shflxor_u64(key, jj);
                    bool up = ((lane & k) == 0);      // k=64 -> all ascending
                    bool lowlane = ((lane & jj) == 0);
                    bool takeMin = (lowlane == up);
                    bool lt = key < other;
                    key = (takeMin == lt) ? key : other;
                }
            }
            // merge into running result (exact: top-40 subset of lower-64)
            if (!have_res) {
                res = key;
                have_res = true;
            } else {
                ull rb = shfl_u64(key, 63 - lane);    // reversed -> descending
                ull lo_ = (res < rb) ? res : rb;      // bitonic lower-64
#pragma unroll
                for (int jj = 32; jj > 0; jj >>= 1) { // cleanup -> sorted
                    ull other = shflxor_u64(lo_, jj);
                    bool lowlane = ((lane & jj) == 0);
                    bool lt = lo_ < other;
                    lo_ = (lowlane == lt) ? lo_ : other;
                }
                res = lo_;
            }
        }
    }
    // coalesced output: lane k writes slot k
    if (lane < KNN)
        op[lane] = (res == INITK) ? (float)SENT : (float)(int)(res & 0x1FFFu);
}

// per-point voxel id (f32 division, f32 dl)
__global__ void vid_kernel(const float* __restrict__ pts,
                           const int* __restrict__ len_ptr, int len_const,
                           int* __restrict__ vid, float dlf, int G) {
    int b = blockIdx.y;
    int i = blockIdx.x * 256 + threadIdx.x;
    int len = len_ptr ? len_ptr[b] : len_const;
    if (i >= len) return;
    const float* p = pts + ((size_t)b * NN + i) * 3;
    int cx = (int)floorf(__fdiv_rn(p[0], dlf));
    int cy = (int)floorf(__fdiv_rn(p[1], dlf));
    int cz = (int)floorf(__fdiv_rn(p[2], dlf));
    cx = min(max(cx, 0), G - 1);
    cy = min(max(cy, 0), G - 1);
    cz = min(max(cz, 0), G - 1);
    vid[(size_t)b * NN + i] = (cx * G + cy) * G + cz;  // lexicographic == ref key order
}

// deterministic per-voxel accumulation, wave-per-voxel (bit-exact ordering)
__global__ __launch_bounds__(256) void vscan_kernel(
    const float* __restrict__ pts, const int* __restrict__ vid,
    const int* __restrict__ len_ptr, int len_const,
    float* __restrict__ vsum, int* __restrict__ vcnt, int G3) {
    int b = blockIdx.y;
    int t = threadIdx.x;
    int w = t >> 6, lane = t & 63;
    int v = blockIdx.x * 4 + w;          // one wave per voxel
    if (v >= G3) return;                 // wave-uniform, no syncthreads in kernel
    int len = len_ptr ? len_ptr[b] : len_const;
    const int* vb = vid + (size_t)b * NN;
    const float* pb = pts + (size_t)b * NN * 3;
    float sx = 0.f, sy = 0.f, sz = 0.f;
    int c = 0;
    for (int base = 0; base < len; base += 64) {
        int i = base + lane;
        int myv = (i < len) ? vb[i] : -1;
        ull m = __ballot(myv == v);
        while (m) {                       // m wave-uniform; body runs on all lanes
            int bit = __ffsll(m) - 1;
            m &= m - 1;                   // clear lowest set bit -> ascending order
            int idx = base + bit;
            sx = __fadd_rn(sx, pb[idx * 3]);
            sy = __fadd_rn(sy, pb[idx * 3 + 1]);
            sz = __fadd_rn(sz, pb[idx * 3 + 2]);
            ++c;
        }
    }
    if (lane == 0) {
        size_t o = (size_t)b * G3 + v;
        vsum[o * 3]     = sx;
        vsum[o * 3 + 1] = sy;
        vsum[o * 3 + 2] = sz;
        vcnt[o] = c;
    }
}

// compact occupied voxels in id (== key) order -> padded means + length.
// MEAN = sum * f32(1/cnt) (reciprocal-multiply — matches the np reference
// EXACTLY; verified bit-exact in R14. DO NOT change to true division.)
__global__ __launch_bounds__(1024) void compact_kernel(
    const float* __restrict__ vsum, const int* __restrict__ vcnt, int G3,
    float* __restrict__ out_pts, int* __restrict__ len_dev,
    float* __restrict__ len_out_f) {
    __shared__ int wsum[16];
    int b = blockIdx.x;
    int t = threadIdx.x;
    int per = (G3 + 1023) >> 10;
    int start = t * per;
    int end = min(start + per, G3);
    if (start > G3) start = G3;
    int c = 0;
    for (int v = start; v < end; ++v) c += (vcnt[(size_t)b * G3 + v] > 0);
    int lane = t & 63, wid = t >> 6;
    int inc = c;
    for (int d = 1; d < 64; d <<= 1) {
        int u = __shfl_up(inc, d);
        if (lane >= d) inc += u;
    }
    if (lane == 63) wsum[wid] = inc;
    __syncthreads();
    if (t < 16) {
        int wv = wsum[t];
        for (int d = 1; d < 16; d <<= 1) {
            int u = __shfl_up(wv, d);
            if (t >= d) wv += u;
        }
        wsum[t] = wv;
    }
    __syncthreads();
    int excl = inc - c + (wid ? wsum[wid - 1] : 0);
    int total = wsum[15];
    int off = excl;
    for (int v = start; v < end; ++v) {
        int cn = vcnt[(size_t)b * G3 + v];
        if (cn > 0) {
            float rinv = __frcp_rn((float)cn);
            const float* sp = vsum + ((size_t)b * G3 + v) * 3;
            float* op = out_pts + ((size_t)b * NN + off) * 3;
            op[0] = __fmul_rn(sp[0], rinv);
            op[1] = __fmul_rn(sp[1], rinv);
            op[2] = __fmul_rn(sp[2], rinv);
            ++off;
        }
    }
    for (int r = total + t; r < NN; r += 1024) {
        float* op = out_pts + ((size_t)b * NN + r) * 3;
        op[0] = 0.f; op[1] = 0.f; op[2] = 0.f;
    }
    if (t == 0) {
        len_dev[b] = total;
        len_out_f[b] = (float)total;
    }
}

extern "C" void kernel_launch(void* const* d_in, const int* in_sizes, int n_in,
                              void* d_out, int out_size, void* d_ws, size_t ws_size,
                              hipStream_t stream) {
    const float* pts = (const float*)d_in[0];
    float* dout = (float*)d_out;
    const size_t PN = (size_t)BB * NN * 3;     // 49152
    const size_t IN = (size_t)BB * NN * KNN;   // 655360
    float* out_points = dout;
    float* out_neigh  = dout + 3 * PN;
    float* out_pool   = out_neigh + 3 * IN;
    float* out_up     = out_pool + 3 * IN;
    float* out_len    = out_up + 3 * IN;
    float* pts1 = out_points + PN;       // layer-1 points live directly in d_out
    float* pts2 = out_points + 2 * PN;

    // workspace layout (everything written before read -> no memset needed)
    int*   vid0  = (int*)d_ws;                               // BB*NN
    int*   vid1  = vid0 + (size_t)BB * NN;                   // BB*NN
    float* vsum0 = (float*)(vid1 + (size_t)BB * NN);         // BB*G0_3*3
    int*   vcnt0 = (int*)(vsum0 + (size_t)BB * G0_3 * 3);    // BB*G0_3
    float* vsum1 = (float*)(vcnt0 + (size_t)BB * G0_3);      // BB*G1_3*3
    int*   vcnt1 = (int*)(vsum1 + (size_t)BB * G1_3 * 3);    // BB*G1_3
    int*   len1  = vcnt1 + (size_t)BB * G1_3;
    int*   len2  = len1 + BB;
    // ball-query CSR arrays
    int*   offA  = len2 + BB;                                // BB*(GA_3+1)
    int*   lstA  = offA + (size_t)BB * (GA_3 + 1);           // BB*NN
    int*   offB  = lstA + (size_t)BB * NN;                   // BB*(GB_3+1)
    int*   lstB  = offB + (size_t)BB * (GB_3 + 1);           // BB*NN
    int*   offC  = lstB + (size_t)BB * NN;                   // BB*(GC_3+1)
    int*   lstC  = offC + (size_t)BB * (GC_3 + 1);           // BB*NN

    // mirror Python double-precision scalar arithmetic, then narrow to f32
    double r_normal = 0.03 * 2.5;                 // 0.075
    double r0 = r_normal;
    double dl0 = 2.0 * r_normal / 2.5;            // 0.06
    float r2_0   = (float)(r0 * r0);
    float r2_up0 = (float)((2.0 * r0) * (2.0 * r0));
    float dlf0   = (float)dl0;
    r_normal *= 2.0;                              // 0.15
    double r1 = r_normal;
    double dl1 = 2.0 * r_normal / 2.5;            // 0.12
    float r2_1   = (float)(r1 * r1);
    float r2_up1 = (float)((2.0 * r1) * (2.0 * r1));
    float dlf1   = (float)dl1;
    r_normal *= 2.0;                              // 0.3
    float r2_2 = (float)(r_normal * r_normal);

    dim3 qgrid(NN / 4, BB);             // bq_wave: one wave per query, 4 waves/block
    dim3 vxgrid(NN / 256, BB);
    dim3 vsgrid0((G0_3 + 3) / 4, BB);   // one wave (of 4 per block) per voxel
    dim3 vsgrid1((G1_3 + 3) / 4, BB);

    prep_kernel<<<(int)((IN + 255) / 256), 256, 0, stream>>>(pts, dout);
    // layer 0  (CSR_A: supports = pts, G=13, serves r=0.075 calls)
    csr_build<<<BB, 1024, 0, stream>>>(pts, nullptr, NN, GA, GA_3, offA, lstA);
    bq_wave<<<qgrid, 256, 0, stream>>>(pts, nullptr, NN, pts, offA, lstA,
                                       GA, GA_3, r2_0, out_neigh + 0 * IN);
    vid_kernel<<<vxgrid, 256, 0, stream>>>(pts, nullptr, NN, vid0, dlf0, G0);
    vscan_kernel<<<vsgrid0, 256, 0, stream>>>(pts, vid0, nullptr, NN, vsum0, vcnt0, G0_3);
    compact_kernel<<<BB, 1024, 0, stream>>>(vsum0, vcnt0, G0_3, pts1, len1, out_len + 2);
    bq_wave<<<qgrid, 256, 0, stream>>>(pts1, len1, 0, pts, offA, lstA,
                                       GA, GA_3, r2_0, out_pool + 0 * IN);
    // CSR_B: supports = pts1, G=6, serves r=0.15 calls (up0, conv1, pool1)
    csr_build<<<BB, 1024, 0, stream>>>(pts1, len1, 0, GB, GB_3, offB, lstB);
    bq_wave<<<qgrid, 256, 0, stream>>>(pts, nullptr, NN, pts1, offB, lstB,
                                       GB, GB_3, r2_up0, out_up + 0 * IN);
    // layer 1
    vid_kernel<<<vxgrid, 256, 0, stream>>>(pts1, len1, 0, vid1, dlf1, G1);
    vscan_kernel<<<vsgrid1, 256, 0, stream>>>(pts1, vid1, len1, 0, vsum1, vcnt1, G1_3);
    compact_kernel<<<BB, 1024, 0, stream>>>(vsum1, vcnt1, G1_3, pts2, len2, out_len + 4);
    bq_wave<<<qgrid, 256, 0, stream>>>(pts1, len1, 0, pts1, offB, lstB,
                                       GB, GB_3, r2_1, out_neigh + 1 * IN);
    bq_wave<<<qgrid, 256, 0, stream>>>(pts2, len2, 0, pts1, offB, lstB,
                                       GB, GB_3, r2_1, out_pool + 1 * IN);
    // CSR_C: supports = pts2, G=3, serves r=0.3 calls (up1, conv2)
    csr_build<<<BB, 1024, 0, stream>>>(pts2, len2, 0, GC, GC_3, offC, lstC);
    bq_wave<<<qgrid, 256, 0, stream>>>(pts1, len1, 0, pts2, offC, lstC,
                                       GC, GC_3, r2_up1, out_up + 1 * IN);
    // layer 2
    bq_wave<<<qgrid, 256, 0, stream>>>(pts2, len2, 0, pts2, offC, lstC,
                                       GC, GC_3, r2_2, out_neigh + 2 * IN);
}

// Round 10
// 254.234 us; speedup vs baseline: 8.4064x; 1.1848x over previous
//
#include <hip/hip_runtime.h>

// ---- static config (mirrors reference) ----
#define BB   2
#define NN   8192
#define KNN  40
#define SENT 8192
#define G0   17          // ceil coords for dl=0.06, pts in [0,1)
#define G1   9           // for dl=0.12
#define G0_3 (G0*G0*G0)  // 4913
#define G1_3 (G1*G1*G1)  // 729

// ball-query CSR grids: G = floor(1/r) so cell = 1/G >= r -> +-1 cells cover
#define GA   13          // r = 0.075  (conv0, pool0) supports = pts
#define GB   6           // r = 0.15   (up0, conv1, pool1) supports = pts1
#define GC   3           // r = 0.3    (up1, conv2) supports = pts2
#define GA_3 (GA*GA*GA)  // 2197
#define GB_3 (GB*GB*GB)  // 216
#define GC_3 (GC*GC*GC)  // 27

typedef unsigned long long ull;
typedef unsigned int       u32;
typedef unsigned short     u16;

// d2 exactly as numpy: (dx*dx + dy*dy) + dz*dz, no FMA contraction
__device__ __forceinline__ float sqdist(float qx, float qy, float qz,
                                        float sx, float sy, float sz) {
    float dx = __fsub_rn(qx, sx);
    float dy = __fsub_rn(qy, sy);
    float dz = __fsub_rn(qz, sz);
    return __fadd_rn(__fadd_rn(__fmul_rn(dx, dx), __fmul_rn(dy, dy)),
                     __fmul_rn(dz, dz));
}

// cell index for ball-query CSR (multiply form; only build/query consistency matters)
__device__ __forceinline__ int cell1(float p, float Gf, int G) {
    int c = (int)floorf(__fmul_rn(p, Gf));
    return min(max(c, 0), G - 1);
}
// cell coord for voxel subsample (DIVISION form — must mirror the reference)
__device__ __forceinline__ int vcell1(float p, float dlf, int G) {
    int c = (int)floorf(__fdiv_rn(p, dlf));
    return min(max(c, 0), G - 1);
}

// u64 cross-lane helpers (2x 32-bit shfl)
__device__ __forceinline__ ull shfl_u64(ull x, int src) {
    int lo = __shfl((int)(u32)x, src);
    int hi = __shfl((int)(u32)(x >> 32), src);
    return ((ull)(u32)hi << 32) | (ull)(u32)lo;
}
__device__ __forceinline__ ull shflxor_u64(ull x, int m) {
    int lo = __shfl_xor((int)(u32)x, m);
    int hi = __shfl_xor((int)(u32)(x >> 32), m);
    return ((ull)(u32)hi << 32) | (ull)(u32)lo;
}

// prep: copy pts -> out_points[0], fill layer-2 pool/up with SENTINEL, len[0]
__global__ void prep_kernel(const float* __restrict__ pts, float* __restrict__ dout) {
    const size_t PN = (size_t)BB * NN * 3;
    const size_t IN = (size_t)BB * NN * KNN;
    float* out_points0 = dout;
    float* out_pool2   = dout + 3 * PN + 3 * IN + 2 * IN;
    float* out_up2     = dout + 3 * PN + 6 * IN + 2 * IN;
    float* out_len     = dout + 3 * PN + 9 * IN;
    int i = blockIdx.x * 256 + threadIdx.x;
    if (i < (int)PN) out_points0[i] = pts[i];
    if (i < (int)IN) {
        out_pool2[i] = (float)SENT;
        out_up2[i]   = (float)SENT;
    }
    if (i == 0) { out_len[0] = (float)NN; out_len[1] = (float)NN; }
}

// ---- CSR build over supports: cnt -> exclusive scan -> scatter ----
// One 1024-thread block per batch.  Scatter order within a cell is
// nondeterministic (LDS atomics) — harmless: top-40 selection by full
// (d2,idx) key is a SET operation, enumeration-order independent.
__global__ __launch_bounds__(1024) void csr_build(
    const float* __restrict__ pts, const int* __restrict__ len_ptr, int len_const,
    int G, int G3, int* __restrict__ off, int* __restrict__ lst) {
    __shared__ int scnt[GA_3];   // max grid 2197 cells
    __shared__ int soff[GA_3];
    __shared__ int wsum[16];
    int b = blockIdx.x;
    int t = threadIdx.x;
    int len = len_ptr ? len_ptr[b] : len_const;
    const float* pb = pts + (size_t)b * NN * 3;
    float Gf = (float)G;
    for (int v = t; v < G3; v += 1024) scnt[v] = 0;
    __syncthreads();
    for (int i = t; i < len; i += 1024) {
        int c = (cell1(pb[i * 3], Gf, G) * G + cell1(pb[i * 3 + 1], Gf, G)) * G
                + cell1(pb[i * 3 + 2], Gf, G);
        atomicAdd(&scnt[c], 1);
    }
    __syncthreads();
    // exclusive scan of scnt -> soff (chunk-per-thread + shfl block scan)
    int per = (G3 + 1023) >> 10;
    int start = t * per, end = min(start + per, G3);
    if (start > G3) start = G3;
    int csum = 0;
    for (int v = start; v < end; ++v) csum += scnt[v];
    int lane = t & 63, wid = t >> 6;
    int inc = csum;
    for (int d = 1; d < 64; d <<= 1) {
        int u = __shfl_up(inc, d);
        if (lane >= d) inc += u;
    }
    if (lane == 63) wsum[wid] = inc;
    __syncthreads();
    if (t < 16) {
        int wv = wsum[t];
        for (int d = 1; d < 16; d <<= 1) {
            int u = __shfl_up(wv, d);
            if (t >= d) wv += u;
        }
        wsum[t] = wv;
    }
    __syncthreads();
    int excl = inc - csum + (wid ? wsum[wid - 1] : 0);
    int run = excl;
    for (int v = start; v < end; ++v) { soff[v] = run; run += scnt[v]; }
    __syncthreads();
    int* offb = off + (size_t)b * (G3 + 1);
    for (int v = t; v < G3; v += 1024) offb[v] = soff[v];
    if (t == 0) offb[G3] = len;
    __syncthreads();                       // done reading scnt as counts
    for (int v = t; v < G3; v += 1024) scnt[v] = 0;   // reuse as cursors
    __syncthreads();
    int* lstb = lst + (size_t)b * NN;
    for (int i = t; i < len; i += 1024) {
        int c = (cell1(pb[i * 3], Gf, G) * G + cell1(pb[i * 3 + 1], Gf, G)) * G
                + cell1(pb[i * 3 + 2], Gf, G);
        int pos = soff[c] + atomicAdd(&scnt[c], 1);
        lstb[pos] = i;
    }
}

// ---- fused voxel-grid subsample: vid + accumulate + compact in one pass ----
// R10: replaces vid/vscan/compact (6 dispatches, and vscan's O(G3*N/64)
// redundant scan) with one per-batch block.  Phases:
//  1) histogram cells (LDS atomics, order-free)
//  2) ONE packed block-scan -> per-cell entry offsets AND occupied-cell rank
//  3) unstable scatter of point indices (order irrelevant: phase 4 re-derives
//     ascending order exactly)
//  4) per cell: select-min-ascending summation (repeatedly pick smallest
//     unused idx) == reference's stable-sort segment_sum association ->
//     bit-identical sums; mean via __frcp_rn multiply (R14-verified EXACT;
//     DO NOT change to true division); write at occupied-rank position
//     (cell-id order == reference key order).
__global__ __launch_bounds__(1024) void subsample_kernel(
    const float* __restrict__ pts, const int* __restrict__ len_ptr, int len_const,
    float dlf, int G, int G3, int* __restrict__ lst,
    float* __restrict__ out_pts, int* __restrict__ len_dev,
    float* __restrict__ len_out_f) {
    __shared__ int scnt[G0_3];   // max grid 4913 cells (19.6 KiB)
    __shared__ int soff[G0_3];
    __shared__ int wsum[16];
    int b = blockIdx.x;
    int t = threadIdx.x;
    int len = len_ptr ? len_ptr[b] : len_const;
    const float* pb = pts + (size_t)b * NN * 3;
    int* lstb = lst + (size_t)b * NN;
    // phase 1: histogram
    for (int v = t; v < G3; v += 1024) scnt[v] = 0;
    __syncthreads();
    for (int i = t; i < len; i += 1024) {
        int c = (vcell1(pb[i * 3], dlf, G) * G + vcell1(pb[i * 3 + 1], dlf, G)) * G
                + vcell1(pb[i * 3 + 2], dlf, G);
        atomicAdd(&scnt[c], 1);
    }
    __syncthreads();
    // phase 2: packed scan (entries<<14 | occupied); entries<=8192, occ<=4913
    int per = (G3 + 1023) >> 10;
    int start = t * per, end = min(start + per, G3);
    if (start > G3) start = G3;
    int centry = 0, cocc = 0;
    for (int v = start; v < end; ++v) { centry += scnt[v]; cocc += (scnt[v] > 0); }
    int pack = (centry << 14) | cocc;
    int lane = t & 63, wid = t >> 6;
    int inc = pack;
    for (int d = 1; d < 64; d <<= 1) {
        int u = __shfl_up(inc, d);
        if (lane >= d) inc += u;
    }
    if (lane == 63) wsum[wid] = inc;
    __syncthreads();
    if (t < 16) {
        int wv = wsum[t];
        for (int d = 1; d < 16; d <<= 1) {
            int u = __shfl_up(wv, d);
            if (t >= d) wv += u;
        }
        wsum[t] = wv;
    }
    __syncthreads();
    int excl  = inc - pack + (wid ? wsum[wid - 1] : 0);
    int eexcl = excl >> 14;
    int oexcl = excl & 16383;
    int total = wsum[15] & 16383;          // occupied-cell count
    int run = eexcl;
    for (int v = start; v < end; ++v) { soff[v] = run; run += scnt[v]; }
    __syncthreads();
    for (int v = t; v < G3; v += 1024) scnt[v] = 0;   // cursors
    __syncthreads();
    // phase 3: scatter (unstable; re-ordered exactly in phase 4)
    for (int i = t; i < len; i += 1024) {
        int c = (vcell1(pb[i * 3], dlf, G) * G + vcell1(pb[i * 3 + 1], dlf, G)) * G
                + vcell1(pb[i * 3 + 2], dlf, G);
        int pos = soff[c] + atomicAdd(&scnt[c], 1);
        lstb[pos] = i;
    }
    __syncthreads();
    // phase 4: per-cell ascending-index sum + mean + compacted write
    int off = oexcl;
    for (int v = start; v < end; ++v) {
        int s = soff[v];
        int e = (v + 1 < G3) ? soff[v + 1] : len;
        int cn = e - s;
        if (cn > 0) {
            float sx = 0.f, sy = 0.f, sz = 0.f;
            int last = -1;
            for (int k = 0; k < cn; ++k) {           // select-min ascending
                int m = 0x7FFFFFFF;
                for (int j = s; j < e; ++j) {
                    int idx = lstb[j];
                    if (idx > last && idx < m) m = idx;
                }
                sx = __fadd_rn(sx, pb[m * 3]);
                sy = __fadd_rn(sy, pb[m * 3 + 1]);
                sz = __fadd_rn(sz, pb[m * 3 + 2]);
                last = m;
            }
            float rinv = __frcp_rn((float)cn);
            float* op = out_pts + ((size_t)b * NN + off) * 3;
            op[0] = __fmul_rn(sx, rinv);
            op[1] = __fmul_rn(sy, rinv);
            op[2] = __fmul_rn(sz, rinv);
            ++off;
        }
    }
    for (int r = total + t; r < NN; r += 1024) {      // zero-pad tail rows
        float* op = out_pts + ((size_t)b * NN + r) * 3;
        op[0] = 0.f; op[1] = 0.f; op[2] = 0.f;
    }
    if (t == 0) {
        len_dev[b] = total;
        len_out_f[b] = (float)total;
    }
}

// ---- grid-pruned radius ball query, one WAVE per query, DUAL launch ----
// blockIdx.z selects a full parameter set (wave-uniform) so two independent
// ball-query calls share one dispatch.  Body identical to the proven R9
// bq_wave (CSR 27-cell prune -> FILL -> sort-8 -> bitonic sort-64 ->
// bitonic merge with running top-40) -> bit-identical output.
__global__ __launch_bounds__(256) void bq_wave2(
    const float* __restrict__ qA, const int* __restrict__ qlApt, int qlAc,
    const float* __restrict__ sA, const int* __restrict__ offAp,
    const int* __restrict__ lstAp, int GpA, int G3pA, float r2A,
    float* __restrict__ outA,
    const float* __restrict__ qB, const int* __restrict__ qlBpt, int qlBc,
    const float* __restrict__ sB, const int* __restrict__ offBp,
    const int* __restrict__ lstBp, int GpB, int G3pB, float r2B,
    float* __restrict__ outB) {
    const ull INITK = ~0ull;
    int z = blockIdx.z;
    const float* qpts = z ? qB : qA;
    const int* qlen_ptr = z ? qlBpt : qlApt;
    int qlen_const = z ? qlBc : qlAc;
    const float* spts = z ? sB : sA;
    const int* off = z ? offBp : offAp;
    const int* lst = z ? lstBp : lstAp;
    int G  = z ? GpB : GpA;
    int G3 = z ? G3pB : G3pA;
    float r2 = z ? r2B : r2A;
    float* out = z ? outB : outA;

    int t = threadIdx.x;
    int lane = t & 63;
    int b = blockIdx.y;
    int qi = blockIdx.x * 4 + (t >> 6);           // one wave per query
    int qlen = qlen_ptr ? qlen_ptr[b] : qlen_const;
    float* op = out + ((size_t)b * NN + qi) * KNN;
    if (qi >= qlen) {                             // wave-uniform
        if (lane < KNN) op[lane] = (float)SENT;
        return;
    }
    const float* qp = qpts + ((size_t)b * NN + qi) * 3;
    float qx = qp[0], qy = qp[1], qz = qp[2];
    float Gf = (float)G;
    int cx = cell1(qx, Gf, G), cy = cell1(qy, Gf, G), cz = cell1(qz, Gf, G);
    const int* offb = off + (size_t)b * (G3 + 1);
    const int* lstb = lst + (size_t)b * NN;
    const float* sp = spts + (size_t)b * NN * 3;

    // lane d<27: neighbor cell (z fastest -> offb reads mostly contiguous)
    int cnt = 0, cst = 0;
    if (lane < 27) {
        int dz = lane % 3 - 1, dy = (lane / 3) % 3 - 1, dxx = lane / 9 - 1;
        int x = cx + dxx, y = cy + dy, zz = cz + dz;
        bool ok = ((unsigned)x < (unsigned)G) & ((unsigned)y < (unsigned)G)
                                              & ((unsigned)zz < (unsigned)G);
        int c = ok ? (x * G + y) * G + zz : 0;
        int s = ok ? offb[c] : 0;
        int e = ok ? offb[c + 1] : 0;
        cnt = e - s;
        cst = s;
    }
    // wave exclusive scan of cnt; excl[27..63] == T (cnt==0 there)
    int incl = cnt;
#pragma unroll
    for (int d_ = 1; d_ < 64; d_ <<= 1) {
        int u = __shfl_up(incl, d_);
        if (lane >= d_) incl += u;
    }
    int excl = incl - cnt;
    int T = __shfl(incl, 63);

    ull res = INITK;                              // lane k<40 holds k-th best
    bool have_res = false;
    for (int r0 = 0; r0 < T; r0 += 512) {
        ull c0 = INITK, c1 = INITK, c2 = INITK, c3 = INITK,
            c4 = INITK, c5 = INITK, c6 = INITK, c7 = INITK;
#define FILL(S, CS) {                                                          \
            int g = r0 + (S) * 64 + lane;                                      \
            bool gok = g < T;                                                  \
            int gc = gok ? g : (T - 1);                                        \
            int d = 0;                                                         \
            if (__shfl(excl, d | 16) <= gc) d |= 16;                           \
            if (__shfl(excl, d | 8)  <= gc) d |= 8;                            \
            if (__shfl(excl, d | 4)  <= gc) d |= 4;                            \
            if (__shfl(excl, d | 2)  <= gc) d |= 2;                            \
            if (__shfl(excl, d | 1)  <= gc) d |= 1;                            \
            int st = __shfl(cst, d), eg = __shfl(excl, d);                     \
            int idx = lstb[st + (gc - eg)];                                    \
            float sx = sp[idx * 3], sy = sp[idx * 3 + 1], sz = sp[idx * 3 + 2];\
            float d2 = sqdist(qx, qy, qz, sx, sy, sz);                         \
            if (gok && d2 <= r2)                                               \
                CS = (((ull)__float_as_uint(d2)) << 13) | (ull)(u32)idx;       \
        }
        FILL(0, c0) FILL(1, c1) FILL(2, c2) FILL(3, c3)
        FILL(4, c4) FILL(5, c5) FILL(6, c6) FILL(7, c7)
#undef FILL
        // per-lane Batcher sort-8 ascending (INITK sinks to back)
#define CE(A, B) { ull lo_ = (A < B) ? A : B; ull hi_ = (A < B) ? B : A; A = lo_; B = hi_; }
        CE(c0,c1) CE(c2,c3) CE(c4,c5) CE(c6,c7)
        CE(c0,c2) CE(c1,c3) CE(c4,c6) CE(c5,c7)
        CE(c1,c2) CE(c5,c6)
        CE(c0,c4) CE(c1,c5) CE(c2,c6) CE(c3,c7)
        CE(c2,c4) CE(c3,c5)
        CE(c1,c2) CE(c3,c4) CE(c5,c6)
#undef CE
        int m = (c0 != INITK) + (c1 != INITK) + (c2 != INITK) + (c3 != INITK)
              + (c4 != INITK) + (c5 != INITK) + (c6 != INITK) + (c7 != INITK);
        int incm = m;
#pragma unroll
        for (int d_ = 1; d_ < 64; d_ <<= 1) {
            int u = __shfl_up(incm, d_);
            if (lane >= d_) incm += u;
        }
        int base = incm - m;
        int M = __shfl(incm, 63);
        int npass = (M + 63) >> 6;                // wave-uniform
        for (int p = 0; p < npass; ++p) {
            int D = p * 64 + lane;
            bool dok = D < M;
            int Dc = dok ? D : (M - 1);           // M >= 1 here
            int l = 0;
            if (__shfl(base, l | 32) <= Dc) l |= 32;
            if (__shfl(base, l | 16) <= Dc) l |= 16;
            if (__shfl(base, l | 8)  <= Dc) l |= 8;
            if (__shfl(base, l | 4)  <= Dc) l |= 4;
            if (__shfl(base, l | 2)  <= Dc) l |= 2;
            if (__shfl(base, l | 1)  <= Dc) l |= 1;
            int j = Dc - __shfl(base, l);         // slot within owner, 0..7
            ull p0 = shfl_u64(c0, l), p1 = shfl_u64(c1, l);
            ull p2 = shfl_u64(c2, l), p3 = shfl_u64(c3, l);
            ull p4 = shfl_u64(c4, l), p5 = shfl_u64(c5, l);
            ull p6 = shfl_u64(c6, l), p7 = shfl_u64(c7, l);
            ull a0 = (j & 1) ? p1 : p0;
            ull a1 = (j & 1) ? p3 : p2;
            ull a2 = (j & 1) ? p5 : p4;
            ull a3 = (j & 1) ? p7 : p6;
            ull b0 = (j & 2) ? a1 : a0;
            ull b1 = (j & 2) ? a3 : a2;
            ull key = (j & 4) ? b1 : b0;
            if (!dok) key = INITK;
            // bitonic sort-64, one key per lane, ascending
#pragma unroll
            for (int k = 2; k <= 64; k <<= 1) {
#pragma unroll
                for (int jj = k >> 1; jj > 0; jj >>= 1) {
                    ull other = shflxor_u64(key, jj);
                    bool up = ((lane & k) == 0);
                    bool lowlane = ((lane & jj) == 0);
                    bool takeMin = (lowlane == up);
                    bool lt = key < other;
                    key = (takeMin == lt) ? key : other;
                }
            }
            // merge into running result (exact: top-40 subset of lower-64)
            if (!have_res) {
                res = key;
                have_res = true;
            } else {
                ull rb = shfl_u64(key, 63 - lane);    // reversed -> descending
                ull lo_ = (res < rb) ? res : rb;      // bitonic lower-64
#pragma unroll
                for (int jj = 32; jj > 0; jj >>= 1) { // cleanup -> sorted
                    ull other = shflxor_u64(lo_, jj);
                    bool lowlane = ((lane & jj) == 0);
                    bool lt = lo_ < other;
                    lo_ = (lowlane == lt) ? lo_ : other;
                }
                res = lo_;
            }
        }
    }
    if (lane < KNN)
        op[lane] = (res == INITK) ? (float)SENT : (float)(int)(res & 0x1FFFu);
}

extern "C" void kernel_launch(void* const* d_in, const int* in_sizes, int n_in,
                              void* d_out, int out_size, void* d_ws, size_t ws_size,
                              hipStream_t stream) {
    const float* pts = (const float*)d_in[0];
    float* dout = (float*)d_out;
    const size_t PN = (size_t)BB * NN * 3;     // 49152
    const size_t IN = (size_t)BB * NN * KNN;   // 655360
    float* out_points = dout;
    float* out_neigh  = dout + 3 * PN;
    float* out_pool   = out_neigh + 3 * IN;
    float* out_up     = out_pool + 3 * IN;
    float* out_len    = out_up + 3 * IN;
    float* pts1 = out_points + PN;       // layer-1 points live directly in d_out
    float* pts2 = out_points + 2 * PN;

    // workspace layout (everything written before read -> no memset needed)
    int*   len1  = (int*)d_ws;                               // BB
    int*   len2  = len1 + BB;                                // BB
    int*   offA  = len2 + BB;                                // BB*(GA_3+1)
    int*   lstA  = offA + (size_t)BB * (GA_3 + 1);           // BB*NN
    int*   offB  = lstA + (size_t)BB * NN;                   // BB*(GB_3+1)
    int*   lstB  = offB + (size_t)BB * (GB_3 + 1);           // BB*NN
    int*   offC  = lstB + (size_t)BB * NN;                   // BB*(GC_3+1)
    int*   lstC  = offC + (size_t)BB * (GC_3 + 1);           // BB*NN
    int*   lstV0 = lstC + (size_t)BB * NN;                   // BB*NN
    int*   lstV1 = lstV0 + (size_t)BB * NN;                  // BB*NN

    // mirror Python double-precision scalar arithmetic, then narrow to f32
    double r_normal = 0.03 * 2.5;                 // 0.075
    double r0 = r_normal;
    double dl0 = 2.0 * r_normal / 2.5;            // 0.06
    float r2_0   = (float)(r0 * r0);
    float r2_up0 = (float)((2.0 * r0) * (2.0 * r0));
    float dlf0   = (float)dl0;
    r_normal *= 2.0;                              // 0.15
    double r1 = r_normal;
    double dl1 = 2.0 * r_normal / 2.5;            // 0.12
    float r2_1   = (float)(r1 * r1);
    float r2_up1 = (float)((2.0 * r1) * (2.0 * r1));
    float dlf1   = (float)dl1;
    r_normal *= 2.0;                              // 0.3
    float r2_2 = (float)(r_normal * r_normal);

    dim3 qgrid1(NN / 4, BB, 1);         // bq_wave2 single call
    dim3 qgrid2(NN / 4, BB, 2);         // bq_wave2 dual call

    prep_kernel<<<(int)((IN + 255) / 256), 256, 0, stream>>>(pts, dout);
    // CSR_A: supports = pts, G=13 (r=0.075)
    csr_build<<<BB, 1024, 0, stream>>>(pts, nullptr, NN, GA, GA_3, offA, lstA);
    // conv0
    bq_wave2<<<qgrid1, 256, 0, stream>>>(
        pts, nullptr, NN, pts, offA, lstA, GA, GA_3, r2_0, out_neigh + 0 * IN,
        pts, nullptr, NN, pts, offA, lstA, GA, GA_3, r2_0, out_neigh + 0 * IN);
    // level-0 subsample -> pts1, len1
    subsample_kernel<<<BB, 1024, 0, stream>>>(pts, nullptr, NN, dlf0, G0, G0_3,
                                              lstV0, pts1, len1, out_len + 2);
    // CSR_B: supports = pts1, G=6 (r=0.15)
    csr_build<<<BB, 1024, 0, stream>>>(pts1, len1, 0, GB, GB_3, offB, lstB);
    // pool0 (q=pts1, s=pts, csrA) + up0 (q=pts, s=pts1, csrB)
    bq_wave2<<<qgrid2, 256, 0, stream>>>(
        pts1, len1, 0, pts, offA, lstA, GA, GA_3, r2_0, out_pool + 0 * IN,
        pts, nullptr, NN, pts1, offB, lstB, GB, GB_3, r2_up0, out_up + 0 * IN);
    // level-1 subsample -> pts2, len2
    subsample_kernel<<<BB, 1024, 0, stream>>>(pts1, len1, 0, dlf1, G1, G1_3,
                                              lstV1, pts2, len2, out_len + 4);
    // conv1 (q=pts1) + pool1 (q=pts2), both s=pts1/csrB
    bq_wave2<<<qgrid2, 256, 0, stream>>>(
        pts1, len1, 0, pts1, offB, lstB, GB, GB_3, r2_1, out_neigh + 1 * IN,
        pts2, len2, 0, pts1, offB, lstB, GB, GB_3, r2_1, out_pool + 1 * IN);
    // CSR_C: supports = pts2, G=3 (r=0.3)
    csr_build<<<BB, 1024, 0, stream>>>(pts2, len2, 0, GC, GC_3, offC, lstC);
    // up1 (q=pts1, s=pts2, csrC) + conv2 (q=pts2, s=pts2, csrC)
    bq_wave2<<<qgrid2, 256, 0, stream>>>(
        pts1, len1, 0, pts2, offC, lstC, GC, GC_3, r2_up1, out_up + 1 * IN,
        pts2, len2, 0, pts2, offC, lstC, GC, GC_3, r2_2, out_neigh + 2 * IN);
}

// Round 11
// 239.565 us; speedup vs baseline: 8.9211x; 1.0612x over previous
//
#include <hip/hip_runtime.h>

// ---- static config (mirrors reference) ----
#define BB   2
#define NN   8192
#define KNN  40
#define SENT 8192
#define G0   17          // ceil coords for dl=0.06, pts in [0,1)
#define G1   9           // for dl=0.12
#define G0_3 (G0*G0*G0)  // 4913
#define G1_3 (G1*G1*G1)  // 729

// ball-query CSR grids: G = floor(1/r) so cell = 1/G >= r -> +-1 cells cover
#define GA   13          // r = 0.075  (conv0, pool0) supports = pts
#define GB   6           // r = 0.15   (up0, conv1, pool1) supports = pts1
#define GC   3           // r = 0.3    (up1, conv2) supports = pts2
#define GA_3 (GA*GA*GA)  // 2197
#define GB_3 (GB*GB*GB)  // 216
#define GC_3 (GC*GC*GC)  // 27

typedef unsigned long long ull;
typedef unsigned int       u32;
typedef unsigned short     u16;

// d2 exactly as numpy: (dx*dx + dy*dy) + dz*dz, no FMA contraction
__device__ __forceinline__ float sqdist(float qx, float qy, float qz,
                                        float sx, float sy, float sz) {
    float dx = __fsub_rn(qx, sx);
    float dy = __fsub_rn(qy, sy);
    float dz = __fsub_rn(qz, sz);
    return __fadd_rn(__fadd_rn(__fmul_rn(dx, dx), __fmul_rn(dy, dy)),
                     __fmul_rn(dz, dz));
}

// cell index for ball-query CSR (multiply form; only build/query consistency matters)
__device__ __forceinline__ int cell1(float p, float Gf, int G) {
    int c = (int)floorf(__fmul_rn(p, Gf));
    return min(max(c, 0), G - 1);
}
// cell coord for voxel subsample (DIVISION form — must mirror the reference)
__device__ __forceinline__ int vcell1(float p, float dlf, int G) {
    int c = (int)floorf(__fdiv_rn(p, dlf));
    return min(max(c, 0), G - 1);
}

// u64 cross-lane helpers (2x 32-bit shfl)
__device__ __forceinline__ ull shfl_u64(ull x, int src) {
    int lo = __shfl((int)(u32)x, src);
    int hi = __shfl((int)(u32)(x >> 32), src);
    return ((ull)(u32)hi << 32) | (ull)(u32)lo;
}
__device__ __forceinline__ ull shflxor_u64(ull x, int m) {
    int lo = __shfl_xor((int)(u32)x, m);
    int hi = __shfl_xor((int)(u32)(x >> 32), m);
    return ((ull)(u32)hi << 32) | (ull)(u32)lo;
}

// prep: copy pts -> out_points[0], SENTINEL fills, len[0], zero voxel cnt arrays
__global__ void prep_kernel(const float* __restrict__ pts, float* __restrict__ dout,
                            int* __restrict__ zbase, int zn) {
    const size_t PN = (size_t)BB * NN * 3;
    const size_t IN = (size_t)BB * NN * KNN;
    float* out_points0 = dout;
    float* out_pool2   = dout + 3 * PN + 3 * IN + 2 * IN;
    float* out_up2     = dout + 3 * PN + 6 * IN + 2 * IN;
    float* out_len     = dout + 3 * PN + 9 * IN;
    int i = blockIdx.x * 256 + threadIdx.x;
    if (i < (int)PN) out_points0[i] = pts[i];
    if (i < (int)IN) {
        out_pool2[i] = (float)SENT;
        out_up2[i]   = (float)SENT;
    }
    if (i < zn) zbase[i] = 0;
    if (i == 0) { out_len[0] = (float)NN; out_len[1] = (float)NN; }
}

// ---- CSR build over supports (+ fused voxel-grid histogram) ----
// One 1024-thread block per batch.  Scatter order within a cell is
// nondeterministic (LDS atomics) — harmless: top-40 selection by full
// (d2,idx) key is a SET operation, enumeration-order independent.
// R11: the voxel-subsample HISTOGRAM rides along in the first point loop
// (same points, division-form cell, global atomicAdd into cntv zeroed by
// prep) — removes a serial phase from the subsample path.
__global__ __launch_bounds__(1024) void csr_build(
    const float* __restrict__ pts, const int* __restrict__ len_ptr, int len_const,
    int G, int G3, int* __restrict__ off, int* __restrict__ lst,
    float dlfv, int Gv, int G3v, int* __restrict__ cntv) {
    __shared__ int scnt[GA_3];   // max grid 2197 cells
    __shared__ int soff[GA_3];
    __shared__ int wsum[16];
    int b = blockIdx.x;
    int t = threadIdx.x;
    int len = len_ptr ? len_ptr[b] : len_const;
    const float* pb = pts + (size_t)b * NN * 3;
    float Gf = (float)G;
    for (int v = t; v < G3; v += 1024) scnt[v] = 0;
    __syncthreads();
    for (int i = t; i < len; i += 1024) {
        float px = pb[i * 3], py = pb[i * 3 + 1], pz = pb[i * 3 + 2];
        int c = (cell1(px, Gf, G) * G + cell1(py, Gf, G)) * G + cell1(pz, Gf, G);
        atomicAdd(&scnt[c], 1);
        if (cntv) {
            int cv = (vcell1(px, dlfv, Gv) * Gv + vcell1(py, dlfv, Gv)) * Gv
                     + vcell1(pz, dlfv, Gv);
            atomicAdd(&cntv[(size_t)b * G3v + cv], 1);
        }
    }
    __syncthreads();
    // exclusive scan of scnt -> soff (chunk-per-thread + shfl block scan)
    int per = (G3 + 1023) >> 10;
    int start = t * per, end = min(start + per, G3);
    if (start > G3) start = G3;
    int csum = 0;
    for (int v = start; v < end; ++v) csum += scnt[v];
    int lane = t & 63, wid = t >> 6;
    int inc = csum;
    for (int d = 1; d < 64; d <<= 1) {
        int u = __shfl_up(inc, d);
        if (lane >= d) inc += u;
    }
    if (lane == 63) wsum[wid] = inc;
    __syncthreads();
    if (t < 16) {
        int wv = wsum[t];
        for (int d = 1; d < 16; d <<= 1) {
            int u = __shfl_up(wv, d);
            if (t >= d) wv += u;
        }
        wsum[t] = wv;
    }
    __syncthreads();
    int excl = inc - csum + (wid ? wsum[wid - 1] : 0);
    int run = excl;
    for (int v = start; v < end; ++v) { soff[v] = run; run += scnt[v]; }
    __syncthreads();
    int* offb = off + (size_t)b * (G3 + 1);
    for (int v = t; v < G3; v += 1024) offb[v] = soff[v];
    if (t == 0) offb[G3] = len;
    __syncthreads();                       // done reading scnt as counts
    for (int v = t; v < G3; v += 1024) scnt[v] = 0;   // reuse as cursors
    __syncthreads();
    int* lstb = lst + (size_t)b * NN;
    for (int i = t; i < len; i += 1024) {
        int c = (cell1(pb[i * 3], Gf, G) * G + cell1(pb[i * 3 + 1], Gf, G)) * G
                + cell1(pb[i * 3 + 2], Gf, G);
        int pos = soff[c] + atomicAdd(&scnt[c], 1);
        lstb[pos] = i;
    }
}

// ---- voxel subsample part A: packed scan + scatter (1 block/batch) ----
// Reads the histogram built in csr_build.  ONE packed block-scan produces
// per-cell entry offsets AND occupied-cell ranks; scatter is unstable
// (LDS cursors) — order re-derived exactly in sub_means.
__global__ __launch_bounds__(1024) void sub_scan_scatter(
    const float* __restrict__ pts, const int* __restrict__ len_ptr, int len_const,
    float dlf, int G, int G3, const int* __restrict__ cntg,
    int* __restrict__ offg, int* __restrict__ rankg, int* __restrict__ lst,
    int* __restrict__ len_dev, float* __restrict__ len_out_f) {
    __shared__ int scnt[G0_3];   // max grid 4913 cells (19.6 KiB)
    __shared__ int soff[G0_3];
    __shared__ int wsum[16];
    int b = blockIdx.x;
    int t = threadIdx.x;
    int len = len_ptr ? len_ptr[b] : len_const;
    const float* pb = pts + (size_t)b * NN * 3;
    int* lstb = lst + (size_t)b * NN;
    for (int v = t; v < G3; v += 1024) scnt[v] = cntg[(size_t)b * G3 + v];
    __syncthreads();
    // packed scan (entries<<14 | occupied); entries<=8192, occ<=4913
    int per = (G3 + 1023) >> 10;
    int start = t * per, end = min(start + per, G3);
    if (start > G3) start = G3;
    int centry = 0, cocc = 0;
    for (int v = start; v < end; ++v) { centry += scnt[v]; cocc += (scnt[v] > 0); }
    int pack = (centry << 14) | cocc;
    int lane = t & 63, wid = t >> 6;
    int inc = pack;
    for (int d = 1; d < 64; d <<= 1) {
        int u = __shfl_up(inc, d);
        if (lane >= d) inc += u;
    }
    if (lane == 63) wsum[wid] = inc;
    __syncthreads();
    if (t < 16) {
        int wv = wsum[t];
        for (int d = 1; d < 16; d <<= 1) {
            int u = __shfl_up(wv, d);
            if (t >= d) wv += u;
        }
        wsum[t] = wv;
    }
    __syncthreads();
    int excl  = inc - pack + (wid ? wsum[wid - 1] : 0);
    int rune = excl >> 14;
    int runo = excl & 16383;
    int total = wsum[15] & 16383;          // occupied-cell count
    int* offb  = offg  + (size_t)b * (G3 + 1);
    int* rankb = rankg + (size_t)b * G3;
    for (int v = start; v < end; ++v) {
        soff[v] = rune;
        offb[v] = rune;
        rankb[v] = runo;                   // rank valid where occupied
        rune += scnt[v];
        runo += (scnt[v] > 0);
    }
    if (t == 0) {
        offb[G3] = len;
        len_dev[b] = total;
        len_out_f[b] = (float)total;
    }
    __syncthreads();
    for (int v = t; v < G3; v += 1024) scnt[v] = 0;   // cursors
    __syncthreads();
    for (int i = t; i < len; i += 1024) {
        int c = (vcell1(pb[i * 3], dlf, G) * G + vcell1(pb[i * 3 + 1], dlf, G)) * G
                + vcell1(pb[i * 3 + 2], dlf, G);
        int pos = soff[c] + atomicAdd(&scnt[c], 1);
        lstb[pos] = i;
    }
}

// ---- voxel subsample part B: per-cell means, thread-per-cell (multi-block) ----
// Select-min-ascending summation (repeatedly pick smallest unused idx) ==
// reference's stable-sort segment_sum association -> bit-identical sums;
// mean via __frcp_rn multiply (R14-verified EXACT; DO NOT change to true
// division).  Write at occupied-rank (cell-id order == reference key order).
// Threads i >= total also zero-pad tail rows.
__global__ __launch_bounds__(256) void sub_means(
    const float* __restrict__ pts, const int* __restrict__ offg,
    const int* __restrict__ rankg, const int* __restrict__ lst,
    const int* __restrict__ len_dev, int G3, float* __restrict__ out_pts) {
    int b = blockIdx.y;
    int i = blockIdx.x * 256 + threadIdx.x;
    const float* pb = pts + (size_t)b * NN * 3;
    const int* offb  = offg + (size_t)b * (G3 + 1);
    const int* lstb  = lst + (size_t)b * NN;
    if (i < G3) {
        int s = offb[i], e = offb[i + 1];
        int cn = e - s;
        if (cn > 0) {
            float sx = 0.f, sy = 0.f, sz = 0.f;
            int last = -1;
            for (int k = 0; k < cn; ++k) {           // select-min ascending
                int m = 0x7FFFFFFF;
                for (int j = s; j < e; ++j) {
                    int idx = lstb[j];
                    if (idx > last && idx < m) m = idx;
                }
                sx = __fadd_rn(sx, pb[m * 3]);
                sy = __fadd_rn(sy, pb[m * 3 + 1]);
                sz = __fadd_rn(sz, pb[m * 3 + 2]);
                last = m;
            }
            float rinv = __frcp_rn((float)cn);
            int rk = rankg[(size_t)b * G3 + i];
            float* op = out_pts + ((size_t)b * NN + rk) * 3;
            op[0] = __fmul_rn(sx, rinv);
            op[1] = __fmul_rn(sy, rinv);
            op[2] = __fmul_rn(sz, rinv);
        }
    }
    int total = len_dev[b];
    if (i >= total && i < NN) {                       // zero-pad tail rows
        float* op = out_pts + ((size_t)b * NN + i) * 3;
        op[0] = 0.f; op[1] = 0.f; op[2] = 0.f;
    }
}

// ---- grid-pruned radius ball query, one WAVE per query, DUAL launch ----
// blockIdx.z selects a full parameter set (wave-uniform).  Proven R9 body:
// CSR 27-cell prune -> FILL -> sort-8 -> bitonic sort-64 -> bitonic merge
// with running top-40 -> bit-identical output.
__global__ __launch_bounds__(256) void bq_wave2(
    const float* __restrict__ qA, const int* __restrict__ qlApt, int qlAc,
    const float* __restrict__ sA, const int* __restrict__ offAp,
    const int* __restrict__ lstAp, int GpA, int G3pA, float r2A,
    float* __restrict__ outA,
    const float* __restrict__ qB, const int* __restrict__ qlBpt, int qlBc,
    const float* __restrict__ sB, const int* __restrict__ offBp,
    const int* __restrict__ lstBp, int GpB, int G3pB, float r2B,
    float* __restrict__ outB) {
    const ull INITK = ~0ull;
    int z = blockIdx.z;
    const float* qpts = z ? qB : qA;
    const int* qlen_ptr = z ? qlBpt : qlApt;
    int qlen_const = z ? qlBc : qlAc;
    const float* spts = z ? sB : sA;
    const int* off = z ? offBp : offAp;
    const int* lst = z ? lstBp : lstAp;
    int G  = z ? GpB : GpA;
    int G3 = z ? G3pB : G3pA;
    float r2 = z ? r2B : r2A;
    float* out = z ? outB : outA;

    int t = threadIdx.x;
    int lane = t & 63;
    int b = blockIdx.y;
    int qi = blockIdx.x * 4 + (t >> 6);           // one wave per query
    int qlen = qlen_ptr ? qlen_ptr[b] : qlen_const;
    float* op = out + ((size_t)b * NN + qi) * KNN;
    if (qi >= qlen) {                             // wave-uniform
        if (lane < KNN) op[lane] = (float)SENT;
        return;
    }
    const float* qp = qpts + ((size_t)b * NN + qi) * 3;
    float qx = qp[0], qy = qp[1], qz = qp[2];
    float Gf = (float)G;
    int cx = cell1(qx, Gf, G), cy = cell1(qy, Gf, G), cz = cell1(qz, Gf, G);
    const int* offb = off + (size_t)b * (G3 + 1);
    const int* lstb = lst + (size_t)b * NN;
    const float* sp = spts + (size_t)b * NN * 3;

    int cnt = 0, cst = 0;
    if (lane < 27) {
        int dz = lane % 3 - 1, dy = (lane / 3) % 3 - 1, dxx = lane / 9 - 1;
        int x = cx + dxx, y = cy + dy, zz = cz + dz;
        bool ok = ((unsigned)x < (unsigned)G) & ((unsigned)y < (unsigned)G)
                                              & ((unsigned)zz < (unsigned)G);
        int c = ok ? (x * G + y) * G + zz : 0;
        int s = ok ? offb[c] : 0;
        int e = ok ? offb[c + 1] : 0;
        cnt = e - s;
        cst = s;
    }
    int incl = cnt;
#pragma unroll
    for (int d_ = 1; d_ < 64; d_ <<= 1) {
        int u = __shfl_up(incl, d_);
        if (lane >= d_) incl += u;
    }
    int excl = incl - cnt;
    int T = __shfl(incl, 63);

    ull res = INITK;                              // lane k<40 holds k-th best
    bool have_res = false;
    for (int r0 = 0; r0 < T; r0 += 512) {
        ull c0 = INITK, c1 = INITK, c2 = INITK, c3 = INITK,
            c4 = INITK, c5 = INITK, c6 = INITK, c7 = INITK;
#define FILL(S, CS) {                                                          \
            int g = r0 + (S) * 64 + lane;                                      \
            bool gok = g < T;                                                  \
            int gc = gok ? g : (T - 1);                                        \
            int d = 0;                                                         \
            if (__shfl(excl, d | 16) <= gc) d |= 16;                           \
            if (__shfl(excl, d | 8)  <= gc) d |= 8;                            \
            if (__shfl(excl, d | 4)  <= gc) d |= 4;                            \
            if (__shfl(excl, d | 2)  <= gc) d |= 2;                            \
            if (__shfl(excl, d | 1)  <= gc) d |= 1;                            \
            int st = __shfl(cst, d), eg = __shfl(excl, d);                     \
            int idx = lstb[st + (gc - eg)];                                    \
            float sx = sp[idx * 3], sy = sp[idx * 3 + 1], sz = sp[idx * 3 + 2];\
            float d2 = sqdist(qx, qy, qz, sx, sy, sz);                         \
            if (gok && d2 <= r2)                                               \
                CS = (((ull)__float_as_uint(d2)) << 13) | (ull)(u32)idx;       \
        }
        FILL(0, c0) FILL(1, c1) FILL(2, c2) FILL(3, c3)
        FILL(4, c4) FILL(5, c5) FILL(6, c6) FILL(7, c7)
#undef FILL
#define CE(A, B) { ull lo_ = (A < B) ? A : B; ull hi_ = (A < B) ? B : A; A = lo_; B = hi_; }
        CE(c0,c1) CE(c2,c3) CE(c4,c5) CE(c6,c7)
        CE(c0,c2) CE(c1,c3) CE(c4,c6) CE(c5,c7)
        CE(c1,c2) CE(c5,c6)
        CE(c0,c4) CE(c1,c5) CE(c2,c6) CE(c3,c7)
        CE(c2,c4) CE(c3,c5)
        CE(c1,c2) CE(c3,c4) CE(c5,c6)
#undef CE
        int m = (c0 != INITK) + (c1 != INITK) + (c2 != INITK) + (c3 != INITK)
              + (c4 != INITK) + (c5 != INITK) + (c6 != INITK) + (c7 != INITK);
        int incm = m;
#pragma unroll
        for (int d_ = 1; d_ < 64; d_ <<= 1) {
            int u = __shfl_up(incm, d_);
            if (lane >= d_) incm += u;
        }
        int base = incm - m;
        int M = __shfl(incm, 63);
        int npass = (M + 63) >> 6;                // wave-uniform
        for (int p = 0; p < npass; ++p) {
            int D = p * 64 + lane;
            bool dok = D < M;
            int Dc = dok ? D : (M - 1);           // M >= 1 here
            int l = 0;
            if (__shfl(base, l | 32) <= Dc) l |= 32;
            if (__shfl(base, l | 16) <= Dc) l |= 16;
            if (__shfl(base, l | 8)  <= Dc) l |= 8;
            if (__shfl(base, l | 4)  <= Dc) l |= 4;
            if (__shfl(base, l | 2)  <= Dc) l |= 2;
            if (__shfl(base, l | 1)  <= Dc) l |= 1;
            int j = Dc - __shfl(base, l);         // slot within owner, 0..7
            ull p0 = shfl_u64(c0, l), p1 = shfl_u64(c1, l);
            ull p2 = shfl_u64(c2, l), p3 = shfl_u64(c3, l);
            ull p4 = shfl_u64(c4, l), p5 = shfl_u64(c5, l);
            ull p6 = shfl_u64(c6, l), p7 = shfl_u64(c7, l);
            ull a0 = (j & 1) ? p1 : p0;
            ull a1 = (j & 1) ? p3 : p2;
            ull a2 = (j & 1) ? p5 : p4;
            ull a3 = (j & 1) ? p7 : p6;
            ull b0 = (j & 2) ? a1 : a0;
            ull b1 = (j & 2) ? a3 : a2;
            ull key = (j & 4) ? b1 : b0;
            if (!dok) key = INITK;
            // bitonic sort-64, one key per lane, ascending
#pragma unroll
            for (int k = 2; k <= 64; k <<= 1) {
#pragma unroll
                for (int jj = k >> 1; jj > 0; jj >>= 1) {
                    ull other = shflxor_u64(key, jj);
                    bool up = ((lane & k) == 0);
                    bool lowlane = ((lane & jj) == 0);
                    bool takeMin = (lowlane == up);
                    bool lt = key < other;
                    key = (takeMin == lt) ? key : other;
                }
            }
            if (!have_res) {
                res = key;
                have_res = true;
            } else {
                ull rb = shfl_u64(key, 63 - lane);    // reversed -> descending
                ull lo_ = (res < rb) ? res : rb;      // bitonic lower-64
#pragma unroll
                for (int jj = 32; jj > 0; jj >>= 1) { // cleanup -> sorted
                    ull other = shflxor_u64(lo_, jj);
                    bool lowlane = ((lane & jj) == 0);
                    bool lt = lo_ < other;
                    lo_ = (lowlane == lt) ? lo_ : other;
                }
                res = lo_;
            }
        }
    }
    if (lane < KNN)
        op[lane] = (res == INITK) ? (float)SENT : (float)(int)(res & 0x1FFFu);
}

extern "C" void kernel_launch(void* const* d_in, const int* in_sizes, int n_in,
                              void* d_out, int out_size, void* d_ws, size_t ws_size,
                              hipStream_t stream) {
    const float* pts = (const float*)d_in[0];
    float* dout = (float*)d_out;
    const size_t PN = (size_t)BB * NN * 3;     // 49152
    const size_t IN = (size_t)BB * NN * KNN;   // 655360
    float* out_points = dout;
    float* out_neigh  = dout + 3 * PN;
    float* out_pool   = out_neigh + 3 * IN;
    float* out_up     = out_pool + 3 * IN;
    float* out_len    = out_up + 3 * IN;
    float* pts1 = out_points + PN;       // layer-1 points live directly in d_out
    float* pts2 = out_points + 2 * PN;

    // workspace layout (cnt arrays zeroed by prep; rest written before read)
    int*   len1  = (int*)d_ws;                               // BB
    int*   len2  = len1 + BB;                                // BB
    int*   cnt0  = len2 + BB;                                // BB*G0_3  (zeroed)
    int*   cnt1  = cnt0 + (size_t)BB * G0_3;                 // BB*G1_3  (zeroed)
    int*   offV0 = cnt1 + (size_t)BB * G1_3;                 // BB*(G0_3+1)
    int*   rnk0  = offV0 + (size_t)BB * (G0_3 + 1);          // BB*G0_3
    int*   lstV0 = rnk0 + (size_t)BB * G0_3;                 // BB*NN
    int*   offV1 = lstV0 + (size_t)BB * NN;                  // BB*(G1_3+1)
    int*   rnk1  = offV1 + (size_t)BB * (G1_3 + 1);          // BB*G1_3
    int*   lstV1 = rnk1 + (size_t)BB * G1_3;                 // BB*NN
    int*   offA  = lstV1 + (size_t)BB * NN;                  // BB*(GA_3+1)
    int*   lstA  = offA + (size_t)BB * (GA_3 + 1);           // BB*NN
    int*   offB  = lstA + (size_t)BB * NN;                   // BB*(GB_3+1)
    int*   lstB  = offB + (size_t)BB * (GB_3 + 1);           // BB*NN
    int*   offC  = lstB + (size_t)BB * NN;                   // BB*(GC_3+1)
    int*   lstC  = offC + (size_t)BB * (GC_3 + 1);           // BB*NN
    int    zn    = BB * (G0_3 + G1_3);                       // cnt0+cnt1 (contiguous)

    // mirror Python double-precision scalar arithmetic, then narrow to f32
    double r_normal = 0.03 * 2.5;                 // 0.075
    double r0 = r_normal;
    double dl0 = 2.0 * r_normal / 2.5;            // 0.06
    float r2_0   = (float)(r0 * r0);
    float r2_up0 = (float)((2.0 * r0) * (2.0 * r0));
    float dlf0   = (float)dl0;
    r_normal *= 2.0;                              // 0.15
    double r1 = r_normal;
    double dl1 = 2.0 * r_normal / 2.5;            // 0.12
    float r2_1   = (float)(r1 * r1);
    float r2_up1 = (float)((2.0 * r1) * (2.0 * r1));
    float dlf1   = (float)dl1;
    r_normal *= 2.0;                              // 0.3
    float r2_2 = (float)(r_normal * r_normal);

    dim3 qgrid1(NN / 4, BB, 1);         // bq_wave2 single call
    dim3 qgrid2(NN / 4, BB, 2);         // bq_wave2 dual call
    dim3 mgrid(NN / 256, BB);           // sub_means: covers max(G3, NN)

    prep_kernel<<<(int)((IN + 255) / 256), 256, 0, stream>>>(pts, dout, cnt0, zn);
    // CSR_A (supports=pts, G=13) + fused level-0 voxel histogram
    csr_build<<<BB, 1024, 0, stream>>>(pts, nullptr, NN, GA, GA_3, offA, lstA,
                                       dlf0, G0, G0_3, cnt0);
    // conv0
    bq_wave2<<<qgrid1, 256, 0, stream>>>(
        pts, nullptr, NN, pts, offA, lstA, GA, GA_3, r2_0, out_neigh + 0 * IN,
        pts, nullptr, NN, pts, offA, lstA, GA, GA_3, r2_0, out_neigh + 0 * IN);
    // level-0 subsample: scan+scatter (1 blk/batch) then means (multi-block)
    sub_scan_scatter<<<BB, 1024, 0, stream>>>(pts, nullptr, NN, dlf0, G0, G0_3,
                                              cnt0, offV0, rnk0, lstV0, len1,
                                              out_len + 2);
    sub_means<<<mgrid, 256, 0, stream>>>(pts, offV0, rnk0, lstV0, len1, G0_3, pts1);
    // CSR_B (supports=pts1, G=6) + fused level-1 voxel histogram
    csr_build<<<BB, 1024, 0, stream>>>(pts1, len1, 0, GB, GB_3, offB, lstB,
                                       dlf1, G1, G1_3, cnt1);
    // pool0 (q=pts1, s=pts, csrA) + up0 (q=pts, s=pts1, csrB)
    bq_wave2<<<qgrid2, 256, 0, stream>>>(
        pts1, len1, 0, pts, offA, lstA, GA, GA_3, r2_0, out_pool + 0 * IN,
        pts, nullptr, NN, pts1, offB, lstB, GB, GB_3, r2_up0, out_up + 0 * IN);
    // level-1 subsample
    sub_scan_scatter<<<BB, 1024, 0, stream>>>(pts1, len1, 0, dlf1, G1, G1_3,
                                              cnt1, offV1, rnk1, lstV1, len2,
                                              out_len + 4);
    sub_means<<<mgrid, 256, 0, stream>>>(pts1, offV1, rnk1, lstV1, len2, G1_3, pts2);
    // conv1 (q=pts1) + pool1 (q=pts2), both s=pts1/csrB
    bq_wave2<<<qgrid2, 256, 0, stream>>>(
        pts1, len1, 0, pts1, offB, lstB, GB, GB_3, r2_1, out_neigh + 1 * IN,
        pts2, len2, 0, pts1, offB, lstB, GB, GB_3, r2_1, out_pool + 1 * IN);
    // CSR_C (supports=pts2, G=3), no voxel histogram
    csr_build<<<BB, 1024, 0, stream>>>(pts2, len2, 0, GC, GC_3, offC, lstC,
                                       0.f, 1, 1, nullptr);
    // up1 (q=pts1, s=pts2, csrC) + conv2 (q=pts2, s=pts2, csrC)
    bq_wave2<<<qgrid2, 256, 0, stream>>>(
        pts1, len1, 0, pts2, offC, lstC, GC, GC_3, r2_up1, out_up + 1 * IN,
        pts2, len2, 0, pts2, offC, lstC, GC, GC_3, r2_2, out_neigh + 2 * IN);
}

// Round 12
// 218.643 us; speedup vs baseline: 9.7748x; 1.0957x over previous
//
#include <hip/hip_runtime.h>

// ---- static config (mirrors reference) ----
#define BB   2
#define NN   8192
#define KNN  40
#define SENT 8192
#define G0   17          // ceil coords for dl=0.06, pts in [0,1)
#define G1   9           // for dl=0.12
#define G0_3 (G0*G0*G0)  // 4913
#define G1_3 (G1*G1*G1)  // 729

// ball-query CSR grids: G = floor(1/r) so cell = 1/G >= r -> +-1 cells cover
#define GA   13          // r = 0.075  (conv0, pool0) supports = pts
#define GB   6           // r = 0.15   (up0, conv1, pool1) supports = pts1
#define GC   3           // r = 0.3    (up1, conv2) supports = pts2
#define GA_3 (GA*GA*GA)  // 2197
#define GB_3 (GB*GB*GB)  // 216
#define GC_3 (GC*GC*GC)  // 27

typedef unsigned long long ull;
typedef unsigned int       u32;
typedef unsigned short     u16;

// d2 exactly as numpy: (dx*dx + dy*dy) + dz*dz, no FMA contraction
__device__ __forceinline__ float sqdist(float qx, float qy, float qz,
                                        float sx, float sy, float sz) {
    float dx = __fsub_rn(qx, sx);
    float dy = __fsub_rn(qy, sy);
    float dz = __fsub_rn(qz, sz);
    return __fadd_rn(__fadd_rn(__fmul_rn(dx, dx), __fmul_rn(dy, dy)),
                     __fmul_rn(dz, dz));
}

// cell index for ball-query CSR (multiply form; only build/query consistency matters)
__device__ __forceinline__ int cell1(float p, float Gf, int G) {
    int c = (int)floorf(__fmul_rn(p, Gf));
    return min(max(c, 0), G - 1);
}
// cell coord for voxel subsample (DIVISION form — must mirror the reference)
__device__ __forceinline__ int vcell1(float p, float dlf, int G) {
    int c = (int)floorf(__fdiv_rn(p, dlf));
    return min(max(c, 0), G - 1);
}

// u64 cross-lane helpers (2x 32-bit shfl)
__device__ __forceinline__ ull shfl_u64(ull x, int src) {
    int lo = __shfl((int)(u32)x, src);
    int hi = __shfl((int)(u32)(x >> 32), src);
    return ((ull)(u32)hi << 32) | (ull)(u32)lo;
}
__device__ __forceinline__ ull shflxor_u64(ull x, int m) {
    int lo = __shfl_xor((int)(u32)x, m);
    int hi = __shfl_xor((int)(u32)(x >> 32), m);
    return ((ull)(u32)hi << 32) | (ull)(u32)lo;
}

// prep: copy pts -> out_points[0], fill layer-2 pool/up with SENTINEL, len[0]
__global__ void prep_kernel(const float* __restrict__ pts, float* __restrict__ dout) {
    const size_t PN = (size_t)BB * NN * 3;
    const size_t IN = (size_t)BB * NN * KNN;
    float* out_points0 = dout;
    float* out_pool2   = dout + 3 * PN + 3 * IN + 2 * IN;
    float* out_up2     = dout + 3 * PN + 6 * IN + 2 * IN;
    float* out_len     = dout + 3 * PN + 9 * IN;
    int i = blockIdx.x * 256 + threadIdx.x;
    if (i < (int)PN) out_points0[i] = pts[i];
    if (i < (int)IN) {
        out_pool2[i] = (float)SENT;
        out_up2[i]   = (float)SENT;
    }
    if (i == 0) { out_len[0] = (float)NN; out_len[1] = (float)NN; }
}

// ---- CSR build over supports + FULLY FUSED voxel-grid subsample prep ----
// One 1024-thread block per batch.  R12: the voxel histogram, packed scan
// (entry offsets + occupied ranks) and scatter all live HERE — only block b
// touches batch b, so its LDS voxel histogram is complete at the barrier
// (removes the separate sub_scan_scatter dispatch and its duplicate point
// pass).  Scatter order within any cell is nondeterministic (LDS atomics) —
// harmless: ball-query top-40 is a set operation, and sub_means re-derives
// ascending order exactly.  LDS: 2*2197 + 2*4913 + 16 ints ~ 57 KiB.
__global__ __launch_bounds__(1024) void csr_build(
    const float* __restrict__ pts, const int* __restrict__ len_ptr, int len_const,
    int G, int G3, int* __restrict__ off, int* __restrict__ lst,
    float dlfv, int Gv, int G3v, int* __restrict__ offv, int* __restrict__ rankv,
    int* __restrict__ lstv, int* __restrict__ lenv_dev, float* __restrict__ lenv_out_f) {
    __shared__ int scnt[GA_3];    // CSR cells (max 2197)
    __shared__ int soff[GA_3];
    __shared__ int svcnt[G0_3];   // voxel cells (max 4913)
    __shared__ int svoff[G0_3];
    __shared__ int wsum[16];
    int b = blockIdx.x;
    int t = threadIdx.x;
    int len = len_ptr ? len_ptr[b] : len_const;
    const float* pb = pts + (size_t)b * NN * 3;
    float Gf = (float)G;
    bool dosub = Gv > 0;          // block-uniform
    for (int v = t; v < G3; v += 1024) scnt[v] = 0;
    if (dosub) for (int v = t; v < G3v; v += 1024) svcnt[v] = 0;
    __syncthreads();
    // phase 1: both histograms in one point pass
    for (int i = t; i < len; i += 1024) {
        float px = pb[i * 3], py = pb[i * 3 + 1], pz = pb[i * 3 + 2];
        int c = (cell1(px, Gf, G) * G + cell1(py, Gf, G)) * G + cell1(pz, Gf, G);
        atomicAdd(&scnt[c], 1);
        if (dosub) {
            int cv = (vcell1(px, dlfv, Gv) * Gv + vcell1(py, dlfv, Gv)) * Gv
                     + vcell1(pz, dlfv, Gv);
            atomicAdd(&svcnt[cv], 1);
        }
    }
    __syncthreads();
    int lane = t & 63, wid = t >> 6;
    // phase 2a: CSR exclusive scan -> soff + global off
    {
        int per = (G3 + 1023) >> 10;
        int start = t * per, end = min(start + per, G3);
        if (start > G3) start = G3;
        int csum = 0;
        for (int v = start; v < end; ++v) csum += scnt[v];
        int inc = csum;
        for (int d = 1; d < 64; d <<= 1) {
            int u = __shfl_up(inc, d);
            if (lane >= d) inc += u;
        }
        if (lane == 63) wsum[wid] = inc;
        __syncthreads();
        if (t < 16) {
            int wv = wsum[t];
            for (int d = 1; d < 16; d <<= 1) {
                int u = __shfl_up(wv, d);
                if (t >= d) wv += u;
            }
            wsum[t] = wv;
        }
        __syncthreads();
        int excl = inc - csum + (wid ? wsum[wid - 1] : 0);
        int run = excl;
        int* offb = off + (size_t)b * (G3 + 1);
        for (int v = start; v < end; ++v) {
            soff[v] = run;
            offb[v] = run;
            run += scnt[v];
        }
        if (t == 0) offb[G3] = len;
    }
    __syncthreads();               // wsum reuse fence
    // phase 2b: voxel packed scan (entries<<14 | occupied) -> svoff + globals
    if (dosub) {
        int per = (G3v + 1023) >> 10;
        int start = t * per, end = min(start + per, G3v);
        if (start > G3v) start = G3v;
        int ce = 0, co = 0;
        for (int v = start; v < end; ++v) { ce += svcnt[v]; co += (svcnt[v] > 0); }
        int pack = (ce << 14) | co;
        int inc = pack;
        for (int d = 1; d < 64; d <<= 1) {
            int u = __shfl_up(inc, d);
            if (lane >= d) inc += u;
        }
        if (lane == 63) wsum[wid] = inc;
        __syncthreads();
        if (t < 16) {
            int wv = wsum[t];
            for (int d = 1; d < 16; d <<= 1) {
                int u = __shfl_up(wv, d);
                if (t >= d) wv += u;
            }
            wsum[t] = wv;
        }
        __syncthreads();
        int excl = inc - pack + (wid ? wsum[wid - 1] : 0);
        int rune = excl >> 14;
        int runo = excl & 16383;
        int total = wsum[15] & 16383;
        int* offvb  = offv  + (size_t)b * (G3v + 1);
        int* rankvb = rankv + (size_t)b * G3v;
        for (int v = start; v < end; ++v) {
            svoff[v]  = rune;
            offvb[v]  = rune;
            rankvb[v] = runo;          // valid where occupied
            rune += svcnt[v];
            runo += (svcnt[v] > 0);
        }
        if (t == 0) {
            offvb[G3v] = len;
            lenv_dev[b] = total;
            lenv_out_f[b] = (float)total;
        }
    }
    __syncthreads();
    // phase 3: reset cursors, scatter both lists in one point pass
    for (int v = t; v < G3; v += 1024) scnt[v] = 0;
    if (dosub) for (int v = t; v < G3v; v += 1024) svcnt[v] = 0;
    __syncthreads();
    int* lstb = lst + (size_t)b * NN;
    int* lstvb = dosub ? (lstv + (size_t)b * NN) : nullptr;
    for (int i = t; i < len; i += 1024) {
        float px = pb[i * 3], py = pb[i * 3 + 1], pz = pb[i * 3 + 2];
        int c = (cell1(px, Gf, G) * G + cell1(py, Gf, G)) * G + cell1(pz, Gf, G);
        int pos = soff[c] + atomicAdd(&scnt[c], 1);
        lstb[pos] = i;
        if (dosub) {
            int cv = (vcell1(px, dlfv, Gv) * Gv + vcell1(py, dlfv, Gv)) * Gv
                     + vcell1(pz, dlfv, Gv);
            int posv = svoff[cv] + atomicAdd(&svcnt[cv], 1);
            lstvb[posv] = i;
        }
    }
}

// ---- voxel subsample part B: per-cell means, thread-per-cell (multi-block) ----
// Select-min-ascending summation (repeatedly pick smallest unused idx) ==
// reference's stable-sort segment_sum association -> bit-identical sums;
// mean via __frcp_rn multiply (R14-verified EXACT; DO NOT change to true
// division).  Write at occupied-rank (cell-id order == reference key order).
// Threads i >= total also zero-pad tail rows.
__global__ __launch_bounds__(256) void sub_means(
    const float* __restrict__ pts, const int* __restrict__ offg,
    const int* __restrict__ rankg, const int* __restrict__ lst,
    const int* __restrict__ len_dev, int G3, float* __restrict__ out_pts) {
    int b = blockIdx.y;
    int i = blockIdx.x * 256 + threadIdx.x;
    const float* pb = pts + (size_t)b * NN * 3;
    const int* offb  = offg + (size_t)b * (G3 + 1);
    const int* lstb  = lst + (size_t)b * NN;
    if (i < G3) {
        int s = offb[i], e = offb[i + 1];
        int cn = e - s;
        if (cn > 0) {
            float sx = 0.f, sy = 0.f, sz = 0.f;
            int last = -1;
            for (int k = 0; k < cn; ++k) {           // select-min ascending
                int m = 0x7FFFFFFF;
                for (int j = s; j < e; ++j) {
                    int idx = lstb[j];
                    if (idx > last && idx < m) m = idx;
                }
                sx = __fadd_rn(sx, pb[m * 3]);
                sy = __fadd_rn(sy, pb[m * 3 + 1]);
                sz = __fadd_rn(sz, pb[m * 3 + 2]);
                last = m;
            }
            float rinv = __frcp_rn((float)cn);
            int rk = rankg[(size_t)b * G3 + i];
            float* op = out_pts + ((size_t)b * NN + rk) * 3;
            op[0] = __fmul_rn(sx, rinv);
            op[1] = __fmul_rn(sy, rinv);
            op[2] = __fmul_rn(sz, rinv);
        }
    }
    int total = len_dev[b];
    if (i >= total && i < NN) {                       // zero-pad tail rows
        float* op = out_pts + ((size_t)b * NN + i) * 3;
        op[0] = 0.f; op[1] = 0.f; op[2] = 0.f;
    }
}

// ---- grid-pruned radius ball query, one WAVE per query, DUAL launch ----
// blockIdx.z selects a full parameter set (wave-uniform).  Proven R9 body:
// CSR 27-cell prune -> FILL -> sort-8 -> bitonic sort-64 -> bitonic merge
// with running top-40 -> bit-identical output.
// R12: FILL slots with r0+S*64 >= T are SKIPPED (T wave-uniform; a skipped
// slot previously produced only INITK, so skipping is exact).  conv0 uses
// ~2 of 8 slots, B-group ~6 of 8.
__global__ __launch_bounds__(256) void bq_wave2(
    const float* __restrict__ qA, const int* __restrict__ qlApt, int qlAc,
    const float* __restrict__ sA, const int* __restrict__ offAp,
    const int* __restrict__ lstAp, int GpA, int G3pA, float r2A,
    float* __restrict__ outA,
    const float* __restrict__ qB, const int* __restrict__ qlBpt, int qlBc,
    const float* __restrict__ sB, const int* __restrict__ offBp,
    const int* __restrict__ lstBp, int GpB, int G3pB, float r2B,
    float* __restrict__ outB) {
    const ull INITK = ~0ull;
    int z = blockIdx.z;
    const float* qpts = z ? qB : qA;
    const int* qlen_ptr = z ? qlBpt : qlApt;
    int qlen_const = z ? qlBc : qlAc;
    const float* spts = z ? sB : sA;
    const int* off = z ? offBp : offAp;
    const int* lst = z ? lstBp : lstAp;
    int G  = z ? GpB : GpA;
    int G3 = z ? G3pB : G3pA;
    float r2 = z ? r2B : r2A;
    float* out = z ? outB : outA;

    int t = threadIdx.x;
    int lane = t & 63;
    int b = blockIdx.y;
    int qi = blockIdx.x * 4 + (t >> 6);           // one wave per query
    int qlen = qlen_ptr ? qlen_ptr[b] : qlen_const;
    float* op = out + ((size_t)b * NN + qi) * KNN;
    if (qi >= qlen) {                             // wave-uniform
        if (lane < KNN) op[lane] = (float)SENT;
        return;
    }
    const float* qp = qpts + ((size_t)b * NN + qi) * 3;
    float qx = qp[0], qy = qp[1], qz = qp[2];
    float Gf = (float)G;
    int cx = cell1(qx, Gf, G), cy = cell1(qy, Gf, G), cz = cell1(qz, Gf, G);
    const int* offb = off + (size_t)b * (G3 + 1);
    const int* lstb = lst + (size_t)b * NN;
    const float* sp = spts + (size_t)b * NN * 3;

    int cnt = 0, cst = 0;
    if (lane < 27) {
        int dz = lane % 3 - 1, dy = (lane / 3) % 3 - 1, dxx = lane / 9 - 1;
        int x = cx + dxx, y = cy + dy, zz = cz + dz;
        bool ok = ((unsigned)x < (unsigned)G) & ((unsigned)y < (unsigned)G)
                                              & ((unsigned)zz < (unsigned)G);
        int c = ok ? (x * G + y) * G + zz : 0;
        int s = ok ? offb[c] : 0;
        int e = ok ? offb[c + 1] : 0;
        cnt = e - s;
        cst = s;
    }
    int incl = cnt;
#pragma unroll
    for (int d_ = 1; d_ < 64; d_ <<= 1) {
        int u = __shfl_up(incl, d_);
        if (lane >= d_) incl += u;
    }
    int excl = incl - cnt;
    int T = __shfl(incl, 63);

    ull res = INITK;                              // lane k<40 holds k-th best
    bool have_res = false;
    for (int r0 = 0; r0 < T; r0 += 512) {
        ull c0 = INITK, c1 = INITK, c2 = INITK, c3 = INITK,
            c4 = INITK, c5 = INITK, c6 = INITK, c7 = INITK;
#define FILL(S, CS) if (r0 + (S) * 64 < T) {                                   \
            int g = r0 + (S) * 64 + lane;                                      \
            bool gok = g < T;                                                  \
            int gc = gok ? g : (T - 1);                                        \
            int d = 0;                                                         \
            if (__shfl(excl, d | 16) <= gc) d |= 16;                           \
            if (__shfl(excl, d | 8)  <= gc) d |= 8;                            \
            if (__shfl(excl, d | 4)  <= gc) d |= 4;                            \
            if (__shfl(excl, d | 2)  <= gc) d |= 2;                            \
            if (__shfl(excl, d | 1)  <= gc) d |= 1;                            \
            int st = __shfl(cst, d), eg = __shfl(excl, d);                     \
            int idx = lstb[st + (gc - eg)];                                    \
            float sx = sp[idx * 3], sy = sp[idx * 3 + 1], sz = sp[idx * 3 + 2];\
            float d2 = sqdist(qx, qy, qz, sx, sy, sz);                         \
            if (gok && d2 <= r2)                                               \
                CS = (((ull)__float_as_uint(d2)) << 13) | (ull)(u32)idx;       \
        }
        FILL(0, c0) FILL(1, c1) FILL(2, c2) FILL(3, c3)
        FILL(4, c4) FILL(5, c5) FILL(6, c6) FILL(7, c7)
#undef FILL
#define CE(A, B) { ull lo_ = (A < B) ? A : B; ull hi_ = (A < B) ? B : A; A = lo_; B = hi_; }
        CE(c0,c1) CE(c2,c3) CE(c4,c5) CE(c6,c7)
        CE(c0,c2) CE(c1,c3) CE(c4,c6) CE(c5,c7)
        CE(c1,c2) CE(c5,c6)
        CE(c0,c4) CE(c1,c5) CE(c2,c6) CE(c3,c7)
        CE(c2,c4) CE(c3,c5)
        CE(c1,c2) CE(c3,c4) CE(c5,c6)
#undef CE
        int m = (c0 != INITK) + (c1 != INITK) + (c2 != INITK) + (c3 != INITK)
              + (c4 != INITK) + (c5 != INITK) + (c6 != INITK) + (c7 != INITK);
        int incm = m;
#pragma unroll
        for (int d_ = 1; d_ < 64; d_ <<= 1) {
            int u = __shfl_up(incm, d_);
            if (lane >= d_) incm += u;
        }
        int base = incm - m;
        int M = __shfl(incm, 63);
        int npass = (M + 63) >> 6;                // wave-uniform
        for (int p = 0; p < npass; ++p) {
            int D = p * 64 + lane;
            bool dok = D < M;
            int Dc = dok ? D : (M - 1);           // M >= 1 here
            int l = 0;
            if (__shfl(base, l | 32) <= Dc) l |= 32;
            if (__shfl(base, l | 16) <= Dc) l |= 16;
            if (__shfl(base, l | 8)  <= Dc) l |= 8;
            if (__shfl(base, l | 4)  <= Dc) l |= 4;
            if (__shfl(base, l | 2)  <= Dc) l |= 2;
            if (__shfl(base, l | 1)  <= Dc) l |= 1;
            int j = Dc - __shfl(base, l);         // slot within owner, 0..7
            ull p0 = shfl_u64(c0, l), p1 = shfl_u64(c1, l);
            ull p2 = shfl_u64(c2, l), p3 = shfl_u64(c3, l);
            ull p4 = shfl_u64(c4, l), p5 = shfl_u64(c5, l);
            ull p6 = shfl_u64(c6, l), p7 = shfl_u64(c7, l);
            ull a0 = (j & 1) ? p1 : p0;
            ull a1 = (j & 1) ? p3 : p2;
            ull a2 = (j & 1) ? p5 : p4;
            ull a3 = (j & 1) ? p7 : p6;
            ull b0 = (j & 2) ? a1 : a0;
            ull b1 = (j & 2) ? a3 : a2;
            ull key = (j & 4) ? b1 : b0;
            if (!dok) key = INITK;
            // bitonic sort-64, one key per lane, ascending
#pragma unroll
            for (int k = 2; k <= 64; k <<= 1) {
#pragma unroll
                for (int jj = k >> 1; jj > 0; jj >>= 1) {
                    ull other = shflxor_u64(key, jj);
                    bool up = ((lane & k) == 0);
                    bool lowlane = ((lane & jj) == 0);
                    bool takeMin = (lowlane == up);
                    bool lt = key < other;
                    key = (takeMin == lt) ? key : other;
                }
            }
            if (!have_res) {
                res = key;
                have_res = true;
            } else {
                ull rb = shfl_u64(key, 63 - lane);    // reversed -> descending
                ull lo_ = (res < rb) ? res : rb;      // bitonic lower-64
#pragma unroll
                for (int jj = 32; jj > 0; jj >>= 1) { // cleanup -> sorted
                    ull other = shflxor_u64(lo_, jj);
                    bool lowlane = ((lane & jj) == 0);
                    bool lt = lo_ < other;
                    lo_ = (lowlane == lt) ? lo_ : other;
                }
                res = lo_;
            }
        }
    }
    if (lane < KNN)
        op[lane] = (res == INITK) ? (float)SENT : (float)(int)(res & 0x1FFFu);
}

extern "C" void kernel_launch(void* const* d_in, const int* in_sizes, int n_in,
                              void* d_out, int out_size, void* d_ws, size_t ws_size,
                              hipStream_t stream) {
    const float* pts = (const float*)d_in[0];
    float* dout = (float*)d_out;
    const size_t PN = (size_t)BB * NN * 3;     // 49152
    const size_t IN = (size_t)BB * NN * KNN;   // 655360
    float* out_points = dout;
    float* out_neigh  = dout + 3 * PN;
    float* out_pool   = out_neigh + 3 * IN;
    float* out_up     = out_pool + 3 * IN;
    float* out_len    = out_up + 3 * IN;
    float* pts1 = out_points + PN;       // layer-1 points live directly in d_out
    float* pts2 = out_points + 2 * PN;

    // workspace layout (everything written before read -> no memset needed)
    int*   len1  = (int*)d_ws;                               // BB
    int*   len2  = len1 + BB;                                // BB
    int*   offV0 = len2 + BB;                                // BB*(G0_3+1)
    int*   rnk0  = offV0 + (size_t)BB * (G0_3 + 1);          // BB*G0_3
    int*   lstV0 = rnk0 + (size_t)BB * G0_3;                 // BB*NN
    int*   offV1 = lstV0 + (size_t)BB * NN;                  // BB*(G1_3+1)
    int*   rnk1  = offV1 + (size_t)BB * (G1_3 + 1);          // BB*G1_3
    int*   lstV1 = rnk1 + (size_t)BB * G1_3;                 // BB*NN
    int*   offA  = lstV1 + (size_t)BB * NN;                  // BB*(GA_3+1)
    int*   lstA  = offA + (size_t)BB * (GA_3 + 1);           // BB*NN
    int*   offB  = lstA + (size_t)BB * NN;                   // BB*(GB_3+1)
    int*   lstB  = offB + (size_t)BB * (GB_3 + 1);           // BB*NN
    int*   offC  = lstB + (size_t)BB * NN;                   // BB*(GC_3+1)
    int*   lstC  = offC + (size_t)BB * (GC_3 + 1);           // BB*NN

    // mirror Python double-precision scalar arithmetic, then narrow to f32
    double r_normal = 0.03 * 2.5;                 // 0.075
    double r0 = r_normal;
    double dl0 = 2.0 * r_normal / 2.5;            // 0.06
    float r2_0   = (float)(r0 * r0);
    float r2_up0 = (float)((2.0 * r0) * (2.0 * r0));
    float dlf0   = (float)dl0;
    r_normal *= 2.0;                              // 0.15
    double r1 = r_normal;
    double dl1 = 2.0 * r_normal / 2.5;            // 0.12
    float r2_1   = (float)(r1 * r1);
    float r2_up1 = (float)((2.0 * r1) * (2.0 * r1));
    float dlf1   = (float)dl1;
    r_normal *= 2.0;                              // 0.3
    float r2_2 = (float)(r_normal * r_normal);

    dim3 qgrid1(NN / 4, BB, 1);         // bq_wave2 single call
    dim3 qgrid2(NN / 4, BB, 2);         // bq_wave2 dual call
    dim3 mgrid(NN / 256, BB);           // sub_means: covers max(G3, NN)

    prep_kernel<<<(int)((IN + 255) / 256), 256, 0, stream>>>(pts, dout);
    // CSR_A (supports=pts, G=13) + fused level-0 voxel scan/scatter
    csr_build<<<BB, 1024, 0, stream>>>(pts, nullptr, NN, GA, GA_3, offA, lstA,
                                       dlf0, G0, G0_3, offV0, rnk0, lstV0,
                                       len1, out_len + 2);
    // level-0 means -> pts1 (multi-block)
    sub_means<<<mgrid, 256, 0, stream>>>(pts, offV0, rnk0, lstV0, len1, G0_3, pts1);
    // conv0
    bq_wave2<<<qgrid1, 256, 0, stream>>>(
        pts, nullptr, NN, pts, offA, lstA, GA, GA_3, r2_0, out_neigh + 0 * IN,
        pts, nullptr, NN, pts, offA, lstA, GA, GA_3, r2_0, out_neigh + 0 * IN);
    // CSR_B (supports=pts1, G=6) + fused level-1 voxel scan/scatter
    csr_build<<<BB, 1024, 0, stream>>>(pts1, len1, 0, GB, GB_3, offB, lstB,
                                       dlf1, G1, G1_3, offV1, rnk1, lstV1,
                                       len2, out_len + 4);
    // level-1 means -> pts2
    sub_means<<<mgrid, 256, 0, stream>>>(pts1, offV1, rnk1, lstV1, len2, G1_3, pts2);
    // pool0 (q=pts1, s=pts, csrA) + up0 (q=pts, s=pts1, csrB)
    bq_wave2<<<qgrid2, 256, 0, stream>>>(
        pts1, len1, 0, pts, offA, lstA, GA, GA_3, r2_0, out_pool + 0 * IN,
        pts, nullptr, NN, pts1, offB, lstB, GB, GB_3, r2_up0, out_up + 0 * IN);
    // conv1 (q=pts1) + pool1 (q=pts2), both s=pts1/csrB
    bq_wave2<<<qgrid2, 256, 0, stream>>>(
        pts1, len1, 0, pts1, offB, lstB, GB, GB_3, r2_1, out_neigh + 1 * IN,
        pts2, len2, 0, pts1, offB, lstB, GB, GB_3, r2_1, out_pool + 1 * IN);
    // CSR_C (supports=pts2, G=3), no voxel work
    csr_build<<<BB, 1024, 0, stream>>>(pts2, len2, 0, GC, GC_3, offC, lstC,
                                       0.f, 0, 0, nullptr, nullptr, nullptr,
                                       nullptr, nullptr);
    // up1 (q=pts1, s=pts2, csrC) + conv2 (q=pts2, s=pts2, csrC)
    bq_wave2<<<qgrid2, 256, 0, stream>>>(
        pts1, len1, 0, pts2, offC, lstC, GC, GC_3, r2_up1, out_up + 1 * IN,
        pts2, len2, 0, pts2, offC, lstC, GC, GC_3, r2_2, out_neigh + 2 * IN);
}